// Round 8
// baseline (854.483 us; speedup 1.0000x reference)
//
#include <hip/hip_runtime.h>
#include <math.h>

// ---- problem constants (fixed shapes) ----
#define NPTS 16384
#define DIM  512
#define KSEL 11                   // K+1 smallest incl. self; min dropped at the end
#define NSPLIT 4
#define CPS   (NPTS / NSPLIT)     // 4096 columns per split
#define BM    128                 // rows per block (4 waves x 32 rows)
#define BN    32                  // columns staged per iteration (32 KB)
#define ITERS (CPS / BN)          // 128 main iterations per split
#define PRE_ITERS 16              // threshold pass: 512 cols per quarter-sample
#define STRIPB 16384              // bytes per 16-row fragment-major strip
#define CAP   192                 // max appended candidates per row

typedef __attribute__((ext_vector_type(4))) float f32x4;
typedef __attribute__((ext_vector_type(8))) short s16x8;

__device__ __forceinline__ unsigned short f2bf(float f) {
    unsigned int x = __float_as_uint(f);
    return (unsigned short)((x + 0x7FFFu + ((x >> 16) & 1u)) >> 16);
}

__device__ __forceinline__ void gload_lds16(const void* g, void* l) {
    __builtin_amdgcn_global_load_lds(
        (const __attribute__((address_space(1))) void*)g,
        (__attribute__((address_space(3))) void*)l, 16, 0, 0);
}

// pin a loaded fragment: value becomes opaque -> compiler cannot rematerialize
__device__ __forceinline__ void pinreg(s16x8& v) { asm volatile("" : "+v"(v)); }

// scalar exact top-KSEL (smallest) scan over v[0..n), n >= KSEL; returns 11th smallest
__device__ __forceinline__ float topk_scan(const float* v, int n, float* a) {
    #pragma unroll
    for (int p = 0; p < KSEL; ++p) a[p] = v[p];
    float mx = a[0];
    #pragma unroll
    for (int p = 1; p < KSEL; ++p) mx = fmaxf(mx, a[p]);
    for (int i = KSEL; i < n; ++i) {
        const float x = v[i];
        if (x < mx) {
            bool done = false;
            #pragma unroll
            for (int p = 0; p < KSEL; ++p) {
                const bool rep = (!done) && (a[p] == mx);
                a[p] = rep ? x : a[p];
                done = done || rep;
            }
            mx = a[0];
            #pragma unroll
            for (int p = 1; p < KSEL; ++p) mx = fmaxf(mx, a[p]);
        }
    }
    return mx;
}

// ---- kernel 1: fused fp32->bf16 convert into fragment-major layout + ||x_i||^2
//   byte(row,k) = (row>>4)*16384 + (k>>5)*1024 + ((k>>3)&3)*256 + (row&15)*16 + (k&7)*2
__global__ void prep_convert(const float* __restrict__ obs, char* __restrict__ obsb,
                             float* __restrict__ sq) {
    const int wv = threadIdx.x >> 6, ln = threadIdx.x & 63;
    const int row = blockIdx.x * 4 + wv;
    const float4* s = (const float4*)(obs + (unsigned long)row * DIM + ln * 8);
    const float4 a = s[0], b = s[1];
    uint4 o;
    o.x = (unsigned int)f2bf(a.x) | ((unsigned int)f2bf(a.y) << 16);
    o.y = (unsigned int)f2bf(a.z) | ((unsigned int)f2bf(a.w) << 16);
    o.z = (unsigned int)f2bf(b.x) | ((unsigned int)f2bf(b.y) << 16);
    o.w = (unsigned int)f2bf(b.z) | ((unsigned int)f2bf(b.w) << 16);
    *(uint4*)(obsb + (unsigned long)(row >> 4) * STRIPB + (ln >> 2) * 1024
              + (ln & 3) * 256 + (row & 15) * 16) = o;
    float ss = a.x*a.x + a.y*a.y + a.z*a.z + a.w*a.w
             + b.x*b.x + b.y*b.y + b.z*b.z + b.w*b.w;
    #pragma unroll
    for (int off = 32; off; off >>= 1) ss += __shfl_xor(ss, off);
    if (ln == 0) sq[row] = ss;
}

// ---- shared GEMM-loop macros (both kernels declare identical local names) ----
#define STAGE(BUF, CITER) do {                                                  \
        const char* gs_ = obsb + (unsigned long)((C0 >> 4) + 2 * (CITER)) * STRIPB \
                          + wv * 8192 + ln * 16;                                \
        char* lb_ = &Braw[BUF][0] + wv * 8192;                                  \
        _Pragma("unroll")                                                       \
        for (int r_ = 0; r_ < 8; ++r_)                                          \
            gload_lds16(gs_ + r_ * 1024, lb_ + r_ * 1024);                      \
    } while (0)

#define GEMM_BODY(CUR, CITER)                                                   \
        const char* bp = &Braw[CUR][0];                                         \
        f32x4 acc[2][2] = {{{0.f,0.f,0.f,0.f},{0.f,0.f,0.f,0.f}},               \
                           {{0.f,0.f,0.f,0.f},{0.f,0.f,0.f,0.f}}};              \
        _Pragma("unroll")                                                       \
        for (int cg = 0; cg < 2; ++cg) {                                        \
            _Pragma("unroll")                                                   \
            for (int t = 0; t < 16; ++t) {                                      \
                const s16x8 b = *(const s16x8*)(bp + cg * STRIPB + t * 1024 + lfrag); \
                acc[0][cg] = __builtin_amdgcn_mfma_f32_16x16x32_bf16(b, afrag[0][t], acc[0][cg], 0, 0, 0); \
                acc[1][cg] = __builtin_amdgcn_mfma_f32_16x16x32_bf16(b, afrag[1][t], acc[1][cg], 0, 0, 0); \
            }                                                                   \
        }                                                                       \
        f32x4 sqv[2];                                                           \
        sqv[0] = *(const f32x4*)(sq + C0 + (CITER) * BN + kc * 4);              \
        sqv[1] = *(const f32x4*)(sq + C0 + (CITER) * BN + 16 + kc * 4);

#define DIST(S, CG, R) fmaf(-2.0f, acc[S][CG][R], sqr[S] + sqv[CG][R])

#define LOAD_AFRAG() do {                                                       \
        _Pragma("unroll")                                                       \
        for (int s = 0; s < 2; ++s) {                                           \
            const unsigned long sbase = (unsigned long)((R0 >> 4) + wv * 2 + s) * STRIPB; \
            _Pragma("unroll")                                                   \
            for (int t = 0; t < 16; ++t) {                                      \
                afrag[s][t] = *(const s16x8*)(obsb + sbase + t * 1024 + lfrag); \
                pinreg(afrag[s][t]);                                            \
            }                                                                   \
            sqr[s] = sq[wrow0 + s * 16 + lr];                                   \
        }                                                                       \
    } while (0)

// ---- kernel 2: shared threshold pass — per (row-tile, quarter) slot-minima -> T_q
//   T_q = 11th smallest of 32 ACTUAL distances (slot minima at distinct columns)
//   => upper bound of the row's true 11th; main pass recomputes bit-identically.
__global__ __launch_bounds__(256, 2) void thresh_pass(
    const char* __restrict__ obsb, const float* __restrict__ sq,
    float* __restrict__ Trow4)
{
    __shared__ __align__(16) char Braw[2][BN * 1024];   // 64 KB double buffer

    const int tid = threadIdx.x;
    const int wv = tid >> 6, ln = tid & 63;
    const int swz = (blockIdx.x & 7) * 64 + (blockIdx.x >> 3);   // XCD-bijective
    const int q  = swz >> 7;                 // quarter-sample 0..3
    const int rt = swz & 127;                // row tile 0..127
    const int R0 = rt * BM;
    const int C0 = q * CPS;                  // sample = first 512 cols of split q
    const int wrow0 = R0 + wv * 32;
    const int lr = ln & 15;
    const int kc = ln >> 4;
    const int lfrag = kc * 256 + lr * 16;

    s16x8 afrag[2][16];
    float sqr[2];
    LOAD_AFRAG();

    float segmin[2][8];
    #pragma unroll
    for (int s = 0; s < 2; ++s)
        #pragma unroll
        for (int p = 0; p < 8; ++p) segmin[s][p] = __builtin_inff();

    STAGE(0, 0);
    __syncthreads();
    #pragma unroll 2
    for (int it = 0; it < PRE_ITERS; ++it) {
        const int cur = it & 1;
        if (it + 1 < PRE_ITERS) STAGE(cur ^ 1, it + 1);
        GEMM_BODY(cur, it);
        #pragma unroll
        for (int s = 0; s < 2; ++s)
            #pragma unroll
            for (int cg = 0; cg < 2; ++cg)
                #pragma unroll
                for (int r = 0; r < 4; ++r)
                    segmin[s][cg * 4 + r] = fminf(segmin[s][cg * 4 + r], DIST(s, cg, r));
        __syncthreads();
    }

    float* mins = (float*)&Braw[0][0];               // [BM][33]
    #pragma unroll
    for (int s = 0; s < 2; ++s)
        #pragma unroll
        for (int p = 0; p < 8; ++p)
            mins[(wv * 32 + s * 16 + lr) * 33 + kc * 8 + p] = segmin[s][p];
    __syncthreads();
    if (tid < BM) {
        float a[KSEL];
        const float T = topk_scan(mins + tid * 33, 32, a);
        Trow4[(R0 + tid) * 4 + q] = T;
    }
}

// ---- kernel 3: main streaming pass — GEMM + filter-append (no heaps, no chains)
__global__ __launch_bounds__(256, 2) void knn_main(
    const char* __restrict__ obsb, const float* __restrict__ sq,
    const float* __restrict__ Trow4, int* __restrict__ cnt,
    float* __restrict__ vals)
{
    __shared__ __align__(16) char Braw[2][BN * 1024];   // 64 KB double buffer

    const int tid = threadIdx.x;
    const int wv = tid >> 6, ln = tid & 63;
    const int swz = (blockIdx.x & 7) * 64 + (blockIdx.x >> 3);   // XCD-bijective
    const int sp = swz >> 7;                 // split 0..3
    const int rt = swz & 127;                // row tile 0..127
    const int R0 = rt * BM;
    const int C0 = sp * CPS;
    const int wrow0 = R0 + wv * 32;
    const int lr = ln & 15;
    const int kc = ln >> 4;
    const int lfrag = kc * 256 + lr * 16;

    s16x8 afrag[2][16];
    float sqr[2];
    LOAD_AFRAG();

    // per-lane row ids and thresholds: T = min over 4 quarter bounds (valid upper bound)
    int rowA[2]; float tval[2];
    #pragma unroll
    for (int s = 0; s < 2; ++s) {
        rowA[s] = wrow0 + s * 16 + lr;
        const f32x4 t4 = *(const f32x4*)(Trow4 + rowA[s] * 4);
        tval[s] = fminf(fminf(t4[0], t4[1]), fminf(t4[2], t4[3]));
    }

#define APP(S, VV) do {                                                         \
        if ((VV) <= tval[S]) {                                                  \
            const int i_ = atomicAdd(&cnt[rowA[S]], 1);                         \
            if (i_ < CAP) vals[(unsigned long)rowA[S] * CAP + i_] = (VV);       \
        }                                                                       \
    } while (0)

    STAGE(0, 0);
    __syncthreads();
    #pragma unroll 2
    for (int it = 0; it < ITERS; ++it) {
        const int cur = it & 1;
        if (it + 1 < ITERS) STAGE(cur ^ 1, it + 1);
        GEMM_BODY(cur, it);
        #pragma unroll
        for (int s = 0; s < 2; ++s) {
            APP(s, DIST(s, 0, 0)); APP(s, DIST(s, 0, 1));
            APP(s, DIST(s, 0, 2)); APP(s, DIST(s, 0, 3));
            APP(s, DIST(s, 1, 0)); APP(s, DIST(s, 1, 1));
            APP(s, DIST(s, 1, 2)); APP(s, DIST(s, 1, 3));
        }
        __syncthreads();
    }
}

// ---- kernel 4: per row, exact top-11 of appended candidates -> output
__global__ void merge_out(const int* __restrict__ cnt, const float* __restrict__ vals,
                          float* __restrict__ out) {
    const int row = blockIdx.x * 256 + threadIdx.x;
    const int n = min(cnt[row], CAP);
    float arr[KSEL];
    topk_scan(vals + (unsigned long)row * CAP, n, arr);
    float mn = arr[0];
    #pragma unroll
    for (int p = 1; p < KSEL; ++p) mn = fminf(mn, arr[p]);
    float ssum = 0.f;
    #pragma unroll
    for (int p = 0; p < KSEL; ++p) ssum += sqrtf(fmaxf(arr[p], 0.f));
    out[row] = log1pf((ssum - sqrtf(fmaxf(mn, 0.f))) * 0.1f);
}

extern "C" void kernel_launch(void* const* d_in, const int* in_sizes, int n_in,
                              void* d_out, int out_size, void* d_ws, size_t ws_size,
                              hipStream_t stream) {
    const float* obs = (const float*)d_in[0];
    float* out = (float*)d_out;
    char* ws = (char*)d_ws;

    char*  obsb  = ws;                                       // 16 MB fragment-major bf16
    float* sq    = (float*)(ws + (size_t)NPTS * 1024);       // 64 KB
    float* Trow4 = sq + NPTS;                                // 256 KB
    int*   cnt   = (int*)(Trow4 + NPTS * 4);                 // 64 KB
    float* vals  = (float*)(cnt + NPTS);                     // 12.6 MB

    hipMemsetAsync(cnt, 0, NPTS * sizeof(int), stream);
    prep_convert<<<NPTS / 4, 256, 0, stream>>>(obs, obsb, sq);
    thresh_pass<<<128 * 4, 256, 0, stream>>>(obsb, sq, Trow4);
    knn_main<<<(NPTS / BM) * NSPLIT, 256, 0, stream>>>(obsb, sq, Trow4, cnt, vals);
    merge_out<<<NPTS / 256, 256, 0, stream>>>(cnt, vals, out);
}

// Round 9
// 591.408 us; speedup vs baseline: 1.4448x; 1.4448x over previous
//
#include <hip/hip_runtime.h>
#include <math.h>

// ---- problem constants (fixed shapes) ----
#define NPTS 16384
#define DIM  512
#define KSEL 11                   // K+1 smallest incl. self; min dropped at the end
#define NSPLIT 4
#define CPS   (NPTS / NSPLIT)     // 4096 columns per split
#define BM    128                 // rows per block (4 waves x 32 rows)
#define BN    16                  // columns per tile (16 KB) -- one fragment strip
#define MITERS (CPS / BN)         // 256 main iterations per split
#define TITERS 32                 // threshold pass: 512 cols per quarter-sample
#define STRIPB 16384              // bytes per 16-row/col fragment-major strip
#define NBUF  3                   // triple buffer: counted-vmcnt pipeline depth 2

typedef __attribute__((ext_vector_type(4))) float f32x4;
typedef __attribute__((ext_vector_type(8))) short s16x8;

__device__ __forceinline__ unsigned short f2bf(float f) {
    unsigned int x = __float_as_uint(f);
    return (unsigned short)((x + 0x7FFFu + ((x >> 16) & 1u)) >> 16);
}

__device__ __forceinline__ void gload_lds16(const void* g, void* l) {
    __builtin_amdgcn_global_load_lds(
        (const __attribute__((address_space(1))) void*)g,
        (__attribute__((address_space(3))) void*)l, 16, 0, 0);
}

// pin a value: becomes opaque -> no remat, and its load is waited HERE (keeps the
// K-loop free of compiler-inserted vmcnt waits that would break counted vmcnt)
__device__ __forceinline__ void pinreg(s16x8& v) { asm volatile("" : "+v"(v)); }
__device__ __forceinline__ void pinf(float& v)   { asm volatile("" : "+v"(v)); }

// scalar exact top-KSEL (smallest) scan over v[0..n), n >= KSEL; returns 11th smallest
__device__ __forceinline__ float topk_scan(const float* v, int n, float* a) {
    #pragma unroll
    for (int p = 0; p < KSEL; ++p) a[p] = v[p];
    float mx = a[0];
    #pragma unroll
    for (int p = 1; p < KSEL; ++p) mx = fmaxf(mx, a[p]);
    for (int i = KSEL; i < n; ++i) {
        const float x = v[i];
        if (x < mx) {
            bool done = false;
            #pragma unroll
            for (int p = 0; p < KSEL; ++p) {
                const bool rep = (!done) && (a[p] == mx);
                a[p] = rep ? x : a[p];
                done = done || rep;
            }
            mx = a[0];
            #pragma unroll
            for (int p = 1; p < KSEL; ++p) mx = fmaxf(mx, a[p]);
        }
    }
    return mx;
}

// ---- kernel 1: fused fp32->bf16 convert into fragment-major layout + ||x_i||^2
//   byte(row,k) = (row>>4)*16384 + (k>>5)*1024 + ((k>>3)&3)*256 + (row&15)*16 + (k&7)*2
__global__ void prep_convert(const float* __restrict__ obs, char* __restrict__ obsb,
                             float* __restrict__ sq) {
    const int wv = threadIdx.x >> 6, ln = threadIdx.x & 63;
    const int row = blockIdx.x * 4 + wv;
    const float4* s = (const float4*)(obs + (unsigned long)row * DIM + ln * 8);
    const float4 a = s[0], b = s[1];
    uint4 o;
    o.x = (unsigned int)f2bf(a.x) | ((unsigned int)f2bf(a.y) << 16);
    o.y = (unsigned int)f2bf(a.z) | ((unsigned int)f2bf(a.w) << 16);
    o.z = (unsigned int)f2bf(b.x) | ((unsigned int)f2bf(b.y) << 16);
    o.w = (unsigned int)f2bf(b.z) | ((unsigned int)f2bf(b.w) << 16);
    *(uint4*)(obsb + (unsigned long)(row >> 4) * STRIPB + (ln >> 2) * 1024
              + (ln & 3) * 256 + (row & 15) * 16) = o;
    float ss = a.x*a.x + a.y*a.y + a.z*a.z + a.w*a.w
             + b.x*b.x + b.y*b.y + b.z*b.z + b.w*b.w;
    #pragma unroll
    for (int off = 32; off; off >>= 1) ss += __shfl_xor(ss, off);
    if (ln == 0) sq[row] = ss;
}

// ---- shared counted-vmcnt pipeline macros ----
// per iter, per wave: exactly 4 gload_lds16 (the ONLY in-loop VMEM ops).
#define STAGE(NB, CIT) do {                                                     \
        const char* gs_ = obsb + (unsigned long)((C0 >> 4) + (CIT)) * STRIPB    \
                          + wv * 4096 + ln * 16;                                \
        char* lb_ = ldsB + (NB) * STRIPB + wv * 4096;                           \
        gload_lds16(gs_,        lb_);                                           \
        gload_lds16(gs_ + 1024, lb_ + 1024);                                    \
        gload_lds16(gs_ + 2048, lb_ + 2048);                                    \
        gload_lds16(gs_ + 3072, lb_ + 3072);                                    \
    } while (0)

#define GEMM_BODY(CITER)                                                        \
        const char* bp = ldsB + bR * STRIPB;                                    \
        f32x4 acc0 = {0.f,0.f,0.f,0.f}, acc1 = {0.f,0.f,0.f,0.f};               \
        _Pragma("unroll")                                                       \
        for (int t = 0; t < 16; ++t) {                                          \
            const s16x8 b = *(const s16x8*)(bp + t * 1024 + lfrag);             \
            acc0 = __builtin_amdgcn_mfma_f32_16x16x32_bf16(b, afrag[0][t], acc0, 0, 0, 0); \
            acc1 = __builtin_amdgcn_mfma_f32_16x16x32_bf16(b, afrag[1][t], acc1, 0, 0, 0); \
        }                                                                       \
        const f32x4 sqv = *(const f32x4*)(sqlds + (CITER) * BN + kc * 4);

#define DIST0(R) fmaf(-2.0f, acc0[R], sqr[0] + sqv[R])
#define DIST1(R) fmaf(-2.0f, acc1[R], sqr[1] + sqv[R])

// boundary: lgkm(0) makes ds_reads of the retiring buffer safe to overwrite;
// vmcnt(4) keeps the iter+2 stage in flight across the barrier (never drain in-loop).
#define BOUNDARY(NIT) do {                                                      \
        if (it < (NIT) - 2) asm volatile("s_waitcnt vmcnt(4) lgkmcnt(0)" ::: "memory"); \
        else                asm volatile("s_waitcnt vmcnt(0) lgkmcnt(0)" ::: "memory"); \
        __builtin_amdgcn_s_barrier();                                           \
        const int tb_ = bR; bR = bM; bM = bS; bS = tb_;                         \
    } while (0)

#define LOAD_AFRAG() do {                                                       \
        _Pragma("unroll")                                                       \
        for (int s = 0; s < 2; ++s) {                                           \
            const unsigned long sbase = (unsigned long)((R0 >> 4) + wv * 2 + s) * STRIPB; \
            _Pragma("unroll")                                                   \
            for (int t = 0; t < 16; ++t) {                                      \
                afrag[s][t] = *(const s16x8*)(obsb + sbase + t * 1024 + lfrag); \
                pinreg(afrag[s][t]);                                            \
            }                                                                   \
            sqr[s] = sq[wrow0 + s * 16 + lr];                                   \
            pinf(sqr[s]);                                                       \
        }                                                                       \
    } while (0)

// ---- kernel 2: shared threshold pass — per (row-tile, quarter) slot-minima -> T_q
//   T_q = 11th smallest of 32 ACTUAL distances (slot minima at distinct columns)
//   => provable upper bound of the row's true 11th smallest.
__global__ __launch_bounds__(256, 2) void thresh_pass(
    const char* __restrict__ obsb, const float* __restrict__ sq,
    float* __restrict__ Trow4)
{
    __shared__ __align__(16) char  ldsB_s[NBUF * STRIPB];   // 48 KB
    __shared__ __align__(16) float sqlds[TITERS * BN];      // 2 KB
    char* ldsB = ldsB_s;

    const int tid = threadIdx.x;
    const int wv = tid >> 6, ln = tid & 63;
    const int swz = (blockIdx.x & 7) * 64 + (blockIdx.x >> 3);   // XCD-bijective
    const int q  = swz >> 7;                 // quarter-sample 0..3
    const int rt = swz & 127;                // row tile 0..127
    const int R0 = rt * BM;
    const int C0 = q * CPS;                  // sample = first 512 cols of split q
    const int wrow0 = R0 + wv * 32;
    const int lr = ln & 15;
    const int kc = ln >> 4;
    const int lfrag = kc * 256 + lr * 16;

    s16x8 afrag[2][16];
    float sqr[2];
    LOAD_AFRAG();
    // stage the 512-float sq sample into LDS (waves 0,1 only; retired in prologue wait)
    if (wv < 2) gload_lds16(sq + C0 + wv * 256 + ln * 4, (char*)sqlds + wv * 1024);

    float segmin[2][8];
    #pragma unroll
    for (int s = 0; s < 2; ++s)
        #pragma unroll
        for (int p = 0; p < 8; ++p) segmin[s][p] = __builtin_inff();

    int bR = 0, bM = 1, bS = 2;
    STAGE(0, 0);
    STAGE(1, 1);
    asm volatile("s_waitcnt vmcnt(4)" ::: "memory");
    __builtin_amdgcn_s_barrier();

    #pragma unroll 2
    for (int it = 0; it < TITERS; ++it) {
        if (it + 2 < TITERS) STAGE(bS, it + 2);
        GEMM_BODY(it);
        #pragma unroll
        for (int r = 0; r < 4; ++r) {
            const int sl = (it & 1) * 4 + r;
            segmin[0][sl] = fminf(segmin[0][sl], DIST0(r));
            segmin[1][sl] = fminf(segmin[1][sl], DIST1(r));
        }
        BOUNDARY(TITERS);
    }

    // gather 32 slot-minima per row (stride 33) -> T_q
    float* mins = (float*)ldsB;              // [BM][33] = 16.9 KB scratch
    #pragma unroll
    for (int s = 0; s < 2; ++s)
        #pragma unroll
        for (int p = 0; p < 8; ++p)
            mins[(wv * 32 + s * 16 + lr) * 33 + kc * 8 + p] = segmin[s][p];
    __syncthreads();
    if (tid < BM) {
        float a[KSEL];
        Trow4[(unsigned long)(R0 + tid) * 4 + q] = topk_scan(mins + tid * 33, 32, a);
    }
}

// ---- kernel 3: main pass — counted-vmcnt pipelined GEMM + seeded register heaps
__global__ __launch_bounds__(256, 2) void knn_main(
    const char* __restrict__ obsb, const float* __restrict__ sq,
    const float* __restrict__ Trow4, float* __restrict__ cand)
{
    __shared__ __align__(16) char  ldsB_s[NBUF * STRIPB];   // 48 KB
    __shared__ __align__(16) float sqlds[CPS];              // 16 KB: split's sq panel
    char* ldsB = ldsB_s;

    const int tid = threadIdx.x;
    const int wv = tid >> 6, ln = tid & 63;
    const int swz = (blockIdx.x & 7) * 64 + (blockIdx.x >> 3);   // XCD-bijective
    const int sp = swz >> 7;                 // split 0..3
    const int rt = swz & 127;                // row tile 0..127
    const int R0 = rt * BM;
    const int C0 = sp * CPS;
    const int wrow0 = R0 + wv * 32;
    const int lr = ln & 15;
    const int kc = ln >> 4;
    const int lfrag = kc * 256 + lr * 16;

    s16x8 afrag[2][16];
    float sqr[2];
    LOAD_AFRAG();
    // stage the split's 4096-float sq panel into LDS (4 ops/wave, retired in prologue)
    #pragma unroll
    for (int j = 0; j < 4; ++j)
        gload_lds16(sq + C0 + j * 1024 + wv * 256 + ln * 4,
                    (char*)sqlds + j * 4096 + wv * 1024);

    // seeded heaps: T = min over 4 quarter bounds (still >= row's true 11th)
    float hp[2][KSEL], hmax[2], mxv[2], tseed[2];
    #pragma unroll
    for (int s = 0; s < 2; ++s) {
        const f32x4 t4 = *(const f32x4*)(Trow4 + (unsigned long)(wrow0 + s * 16 + lr) * 4);
        tseed[s] = fminf(fminf(t4[0], t4[1]), fminf(t4[2], t4[3])) + 1e-3f;
        pinf(tseed[s]);
        #pragma unroll
        for (int p = 0; p < KSEL; ++p) hp[s][p] = __builtin_inff();
        hmax[s] = __builtin_inff();
        mxv[s]  = tseed[s];
    }

#define INS(S, VV) do {                                                         \
        if (__any((VV) < mxv[S])) {                                             \
            const bool ins_ = (VV) < mxv[S];                                    \
            bool done_ = !ins_;                                                 \
            _Pragma("unroll")                                                   \
            for (int p = 0; p < KSEL; ++p) {                                    \
                const bool rep_ = (!done_) && (hp[S][p] == hmax[S]);            \
                hp[S][p] = rep_ ? (VV) : hp[S][p];                              \
                done_ = done_ || rep_;                                          \
            }                                                                   \
            float m_ = hp[S][0];                                                \
            _Pragma("unroll")                                                   \
            for (int p = 1; p < KSEL; ++p) m_ = fmaxf(m_, hp[S][p]);            \
            hmax[S] = m_;                                                       \
            mxv[S]  = fminf(tseed[S], m_);                                      \
        }                                                                       \
    } while (0)

    int bR = 0, bM = 1, bS = 2;
    STAGE(0, 0);
    STAGE(1, 1);
    asm volatile("s_waitcnt vmcnt(4)" ::: "memory");
    __builtin_amdgcn_s_barrier();

    for (int it = 0; it < MITERS; ++it) {
        if (it + 2 < MITERS) STAGE(bS, it + 2);
        GEMM_BODY(it);
        {
            const float w0 = DIST0(0), w1 = DIST0(1), w2 = DIST0(2), w3 = DIST0(3);
            const float x0 = DIST1(0), x1 = DIST1(1), x2 = DIST1(2), x3 = DIST1(3);
            INS(0, w0); INS(0, w1); INS(0, w2); INS(0, w3);
            INS(1, x0); INS(1, x1); INS(1, x2); INS(1, x3);
        }
        BOUNDARY(MITERS);
    }

    // merge 4 lanes x 11 per row -> exact top-11 of this split (stride 45, pad)
    float* sc2 = (float*)ldsB;               // [BM][45] = 23 KB scratch
    #pragma unroll
    for (int s = 0; s < 2; ++s)
        #pragma unroll
        for (int p = 0; p < KSEL; ++p)
            sc2[(wv * 32 + s * 16 + lr) * 45 + kc * KSEL + p] = hp[s][p];
    __syncthreads();
    if (tid < BM) {
        float a[KSEL];
        topk_scan(sc2 + tid * 45, 44, a);
        #pragma unroll
        for (int p = 0; p < KSEL; ++p)
            cand[(unsigned long)(R0 + tid) * (NSPLIT * KSEL) + sp * KSEL + p] = a[p];
    }
}

// ---- kernel 4: merge 4x11 split candidates per row -> output
__global__ void merge_out(const float* __restrict__ cand, float* __restrict__ out) {
    const int row = blockIdx.x * 256 + threadIdx.x;
    const float* c = cand + (unsigned long)row * (NSPLIT * KSEL);
    float arr[KSEL];
    topk_scan(c, NSPLIT * KSEL, arr);
    float mn = arr[0];
    #pragma unroll
    for (int p = 1; p < KSEL; ++p) mn = fminf(mn, arr[p]);
    float ssum = 0.f;
    #pragma unroll
    for (int p = 0; p < KSEL; ++p) ssum += sqrtf(fmaxf(arr[p], 0.f));
    out[row] = log1pf((ssum - sqrtf(fmaxf(mn, 0.f))) * 0.1f);
}

extern "C" void kernel_launch(void* const* d_in, const int* in_sizes, int n_in,
                              void* d_out, int out_size, void* d_ws, size_t ws_size,
                              hipStream_t stream) {
    const float* obs = (const float*)d_in[0];
    float* out = (float*)d_out;
    char* ws = (char*)d_ws;

    char*  obsb  = ws;                                       // 16 MB fragment-major bf16
    float* sq    = (float*)(ws + (size_t)NPTS * 1024);       // 64 KB
    float* Trow4 = sq + NPTS;                                // 256 KB
    float* cand  = Trow4 + NPTS * 4;                         // 2.9 MB

    prep_convert<<<NPTS / 4, 256, 0, stream>>>(obs, obsb, sq);
    thresh_pass<<<128 * 4, 256, 0, stream>>>(obsb, sq, Trow4);
    knn_main<<<128 * NSPLIT, 256, 0, stream>>>(obsb, sq, Trow4, cand);
    merge_out<<<NPTS / 256, 256, 0, stream>>>(cand, out);
}

// Round 10
// 520.283 us; speedup vs baseline: 1.6423x; 1.1367x over previous
//
#include <hip/hip_runtime.h>
#include <math.h>

// ---- problem constants (fixed shapes) ----
#define NPTS 16384
#define DIM  512
#define KSEL 11                   // K+1 smallest incl. self; min dropped at the end
#define NSPLIT 4
#define CPS   (NPTS / NSPLIT)     // 4096 columns per split
#define BM    128                 // rows per block (4 waves x 32 rows)
#define BN    32                  // columns staged per iteration (32 KB)
#define MITERS (CPS / BN)         // 128 main iterations per split
#define TITERS 16                 // threshold pass: 512 cols per quarter-sample
#define STRIPB 16384              // bytes per 16-row/col fragment-major strip

typedef __attribute__((ext_vector_type(4))) float f32x4;
typedef __attribute__((ext_vector_type(8))) short s16x8;

__device__ __forceinline__ unsigned short f2bf(float f) {
    unsigned int x = __float_as_uint(f);
    return (unsigned short)((x + 0x7FFFu + ((x >> 16) & 1u)) >> 16);
}

__device__ __forceinline__ void gload_lds16(const void* g, void* l) {
    __builtin_amdgcn_global_load_lds(
        (const __attribute__((address_space(1))) void*)g,
        (__attribute__((address_space(3))) void*)l, 16, 0, 0);
}

// pin a loaded value: opaque -> compiler cannot rematerialize
__device__ __forceinline__ void pinreg(s16x8& v) { asm volatile("" : "+v"(v)); }
__device__ __forceinline__ void pinf(float& v)   { asm volatile("" : "+v"(v)); }

// scalar exact top-KSEL (smallest) scan over v[0..n), n >= KSEL; returns 11th smallest
__device__ __forceinline__ float topk_scan(const float* v, int n, float* a) {
    #pragma unroll
    for (int p = 0; p < KSEL; ++p) a[p] = v[p];
    float mx = a[0];
    #pragma unroll
    for (int p = 1; p < KSEL; ++p) mx = fmaxf(mx, a[p]);
    for (int i = KSEL; i < n; ++i) {
        const float x = v[i];
        if (x < mx) {
            bool done = false;
            #pragma unroll
            for (int p = 0; p < KSEL; ++p) {
                const bool rep = (!done) && (a[p] == mx);
                a[p] = rep ? x : a[p];
                done = done || rep;
            }
            mx = a[0];
            #pragma unroll
            for (int p = 1; p < KSEL; ++p) mx = fmaxf(mx, a[p]);
        }
    }
    return mx;
}

// ---- kernel 1: fused fp32->bf16 convert into fragment-major layout + ||x_i||^2
//   byte(row,k) = (row>>4)*16384 + (k>>5)*1024 + ((k>>3)&3)*256 + (row&15)*16 + (k&7)*2
__global__ void prep_convert(const float* __restrict__ obs, char* __restrict__ obsb,
                             float* __restrict__ sq) {
    const int wv = threadIdx.x >> 6, ln = threadIdx.x & 63;
    const int row = blockIdx.x * 4 + wv;
    const float4* s = (const float4*)(obs + (unsigned long)row * DIM + ln * 8);
    const float4 a = s[0], b = s[1];
    uint4 o;
    o.x = (unsigned int)f2bf(a.x) | ((unsigned int)f2bf(a.y) << 16);
    o.y = (unsigned int)f2bf(a.z) | ((unsigned int)f2bf(a.w) << 16);
    o.z = (unsigned int)f2bf(b.x) | ((unsigned int)f2bf(b.y) << 16);
    o.w = (unsigned int)f2bf(b.z) | ((unsigned int)f2bf(b.w) << 16);
    *(uint4*)(obsb + (unsigned long)(row >> 4) * STRIPB + (ln >> 2) * 1024
              + (ln & 3) * 256 + (row & 15) * 16) = o;
    float ss = a.x*a.x + a.y*a.y + a.z*a.z + a.w*a.w
             + b.x*b.x + b.y*b.y + b.z*b.z + b.w*b.w;
    #pragma unroll
    for (int off = 32; off; off >>= 1) ss += __shfl_xor(ss, off);
    if (ln == 0) sq[row] = ss;
}

// ---- shared 2-phase double-buffer GEMM macros (R3 cadence, R7 linear layout) ----
#define STAGE(BUF, CITER) do {                                                  \
        const char* gs_ = obsb + (unsigned long)((C0 >> 4) + 2 * (CITER)) * STRIPB \
                          + wv * 8192 + ln * 16;                                \
        char* lb_ = &Braw[BUF][0] + wv * 8192;                                  \
        _Pragma("unroll")                                                       \
        for (int r_ = 0; r_ < 8; ++r_)                                          \
            gload_lds16(gs_ + r_ * 1024, lb_ + r_ * 1024);                      \
    } while (0)

#define GEMM_BODY(CUR, CITER)                                                   \
        const char* bp = &Braw[CUR][0];                                         \
        f32x4 acc[2][2] = {{{0.f,0.f,0.f,0.f},{0.f,0.f,0.f,0.f}},               \
                           {{0.f,0.f,0.f,0.f},{0.f,0.f,0.f,0.f}}};              \
        _Pragma("unroll")                                                       \
        for (int cg = 0; cg < 2; ++cg) {                                        \
            _Pragma("unroll")                                                   \
            for (int t = 0; t < 16; ++t) {                                      \
                const s16x8 b = *(const s16x8*)(bp + cg * STRIPB + t * 1024 + lfrag); \
                acc[0][cg] = __builtin_amdgcn_mfma_f32_16x16x32_bf16(b, afrag[0][t], acc[0][cg], 0, 0, 0); \
                acc[1][cg] = __builtin_amdgcn_mfma_f32_16x16x32_bf16(b, afrag[1][t], acc[1][cg], 0, 0, 0); \
            }                                                                   \
        }                                                                       \
        f32x4 sqv[2];                                                           \
        sqv[0] = *(const f32x4*)(sq + C0 + (CITER) * BN + kc * 4);              \
        sqv[1] = *(const f32x4*)(sq + C0 + (CITER) * BN + 16 + kc * 4);

#define DIST(S, CG, R) fmaf(-2.0f, acc[S][CG][R], sqr[S] + sqv[CG][R])

#define LOAD_AFRAG() do {                                                       \
        _Pragma("unroll")                                                       \
        for (int s = 0; s < 2; ++s) {                                           \
            const unsigned long sbase = (unsigned long)((R0 >> 4) + wv * 2 + s) * STRIPB; \
            _Pragma("unroll")                                                   \
            for (int t = 0; t < 16; ++t) {                                      \
                afrag[s][t] = *(const s16x8*)(obsb + sbase + t * 1024 + lfrag); \
                pinreg(afrag[s][t]);                                            \
            }                                                                   \
            sqr[s] = sq[wrow0 + s * 16 + lr];                                   \
            pinf(sqr[s]);                                                       \
        }                                                                       \
    } while (0)

// ---- kernel 2: shared threshold pass — per (row-tile, quarter) slot-minima -> T_q
//   T_q = 11th smallest of 32 ACTUAL distances (slot minima at distinct columns)
//   => provable upper bound of the row's true 11th smallest.
__global__ __launch_bounds__(256, 2) void thresh_pass(
    const char* __restrict__ obsb, const float* __restrict__ sq,
    float* __restrict__ Trow4)
{
    __shared__ __align__(16) char Braw[2][BN * 1024];   // 64 KB double buffer

    const int tid = threadIdx.x;
    const int wv = tid >> 6, ln = tid & 63;
    const int q  = blockIdx.x >> 7;          // quarter-sample 0..3
    const int rt = blockIdx.x & 127;         // row tile 0..127
    const int R0 = rt * BM;
    const int C0 = q * CPS;                  // sample = first 512 cols of split q
    const int wrow0 = R0 + wv * 32;
    const int lr = ln & 15;
    const int kc = ln >> 4;
    const int lfrag = kc * 256 + lr * 16;

    s16x8 afrag[2][16];
    float sqr[2];
    LOAD_AFRAG();

    float segmin[2][8];
    #pragma unroll
    for (int s = 0; s < 2; ++s)
        #pragma unroll
        for (int p = 0; p < 8; ++p) segmin[s][p] = __builtin_inff();

    STAGE(0, 0);
    __syncthreads();
    #pragma unroll 2
    for (int it = 0; it < TITERS; ++it) {
        const int cur = it & 1;
        if (it + 1 < TITERS) STAGE(cur ^ 1, it + 1);
        GEMM_BODY(cur, it);
        #pragma unroll
        for (int s = 0; s < 2; ++s)
            #pragma unroll
            for (int cg = 0; cg < 2; ++cg)
                #pragma unroll
                for (int r = 0; r < 4; ++r)
                    segmin[s][cg * 4 + r] = fminf(segmin[s][cg * 4 + r], DIST(s, cg, r));
        __syncthreads();
    }

    // gather 32 slot-minima per row (stride 33) -> T_q
    float* mins = (float*)&Braw[0][0];               // [BM][33]
    #pragma unroll
    for (int s = 0; s < 2; ++s)
        #pragma unroll
        for (int p = 0; p < 8; ++p)
            mins[(wv * 32 + s * 16 + lr) * 33 + kc * 8 + p] = segmin[s][p];
    __syncthreads();
    if (tid < BM) {
        float a[KSEL];
        Trow4[(unsigned long)(R0 + tid) * 4 + q] = topk_scan(mins + tid * 33, 32, a);
    }
}

// ---- kernel 3: main pass — 128-iter GEMM + seeded per-lane register heaps (exact)
__global__ __launch_bounds__(256, 2) void knn_main(
    const char* __restrict__ obsb, const float* __restrict__ sq,
    const float* __restrict__ Trow4, float* __restrict__ cand)
{
    __shared__ __align__(16) char Braw[2][BN * 1024];   // 64 KB double buffer

    const int tid = threadIdx.x;
    const int wv = tid >> 6, ln = tid & 63;
    const int sp = blockIdx.x >> 7;          // split 0..3
    const int rt = blockIdx.x & 127;         // row tile 0..127
    const int R0 = rt * BM;
    const int C0 = sp * CPS;
    const int wrow0 = R0 + wv * 32;
    const int lr = ln & 15;
    const int kc = ln >> 4;
    const int lfrag = kc * 256 + lr * 16;

    s16x8 afrag[2][16];
    float sqr[2];
    LOAD_AFRAG();

    // seeded heaps: T = min over 4 quarter bounds (>= row's true 11th => exact gate)
    float hp[2][KSEL], hmax[2], mxv[2], tseed[2];
    #pragma unroll
    for (int s = 0; s < 2; ++s) {
        const f32x4 t4 = *(const f32x4*)(Trow4 + (unsigned long)(wrow0 + s * 16 + lr) * 4);
        tseed[s] = fminf(fminf(t4[0], t4[1]), fminf(t4[2], t4[3])) + 1e-3f;
        pinf(tseed[s]);
        #pragma unroll
        for (int p = 0; p < KSEL; ++p) hp[s][p] = __builtin_inff();
        hmax[s] = __builtin_inff();
        mxv[s]  = tseed[s];
    }

#define INS(S, VV) do {                                                         \
        if (__any((VV) < mxv[S])) {                                             \
            const bool ins_ = (VV) < mxv[S];                                    \
            bool done_ = !ins_;                                                 \
            _Pragma("unroll")                                                   \
            for (int p = 0; p < KSEL; ++p) {                                    \
                const bool rep_ = (!done_) && (hp[S][p] == hmax[S]);            \
                hp[S][p] = rep_ ? (VV) : hp[S][p];                              \
                done_ = done_ || rep_;                                          \
            }                                                                   \
            float m_ = hp[S][0];                                                \
            _Pragma("unroll")                                                   \
            for (int p = 1; p < KSEL; ++p) m_ = fmaxf(m_, hp[S][p]);            \
            hmax[S] = m_;                                                       \
            mxv[S]  = fminf(tseed[S], m_);                                      \
        }                                                                       \
    } while (0)

#define PHASEB_STRIP(S) do {                                                    \
        const float w0 = DIST(S,0,0), w1 = DIST(S,0,1), w2 = DIST(S,0,2), w3 = DIST(S,0,3); \
        const float w4 = DIST(S,1,0), w5 = DIST(S,1,1), w6 = DIST(S,1,2), w7 = DIST(S,1,3); \
        INS(S,w0); INS(S,w1); INS(S,w2); INS(S,w3);                             \
        INS(S,w4); INS(S,w5); INS(S,w6); INS(S,w7);                             \
    } while (0)

    STAGE(0, 0);
    __syncthreads();
    #pragma unroll 2
    for (int it = 0; it < MITERS; ++it) {
        const int cur = it & 1;
        if (it + 1 < MITERS) STAGE(cur ^ 1, it + 1);
        GEMM_BODY(cur, it);
        PHASEB_STRIP(0);
        PHASEB_STRIP(1);
        __syncthreads();
    }

    // merge 4 lanes x 11 per row -> exact top-11 of this split (stride 45, pad)
    float* sc2 = (float*)&Braw[0][0];                // [BM][45] = 23 KB
    #pragma unroll
    for (int s = 0; s < 2; ++s)
        #pragma unroll
        for (int p = 0; p < KSEL; ++p)
            sc2[(wv * 32 + s * 16 + lr) * 45 + kc * KSEL + p] = hp[s][p];
    __syncthreads();
    if (tid < BM) {
        float a[KSEL];
        topk_scan(sc2 + tid * 45, 44, a);
        #pragma unroll
        for (int p = 0; p < KSEL; ++p)
            cand[(unsigned long)(R0 + tid) * (NSPLIT * KSEL) + sp * KSEL + p] = a[p];
    }
}

// ---- kernel 4: merge 4x11 split candidates per row -> output
__global__ void merge_out(const float* __restrict__ cand, float* __restrict__ out) {
    const int row = blockIdx.x * 256 + threadIdx.x;
    const float* c = cand + (unsigned long)row * (NSPLIT * KSEL);
    float arr[KSEL];
    topk_scan(c, NSPLIT * KSEL, arr);
    float mn = arr[0];
    #pragma unroll
    for (int p = 1; p < KSEL; ++p) mn = fminf(mn, arr[p]);
    float ssum = 0.f;
    #pragma unroll
    for (int p = 0; p < KSEL; ++p) ssum += sqrtf(fmaxf(arr[p], 0.f));
    out[row] = log1pf((ssum - sqrtf(fmaxf(mn, 0.f))) * 0.1f);
}

extern "C" void kernel_launch(void* const* d_in, const int* in_sizes, int n_in,
                              void* d_out, int out_size, void* d_ws, size_t ws_size,
                              hipStream_t stream) {
    const float* obs = (const float*)d_in[0];
    float* out = (float*)d_out;
    char* ws = (char*)d_ws;

    char*  obsb  = ws;                                       // 16 MB fragment-major bf16
    float* sq    = (float*)(ws + (size_t)NPTS * 1024);       // 64 KB
    float* Trow4 = sq + NPTS;                                // 256 KB
    float* cand  = Trow4 + NPTS * 4;                         // 2.9 MB

    prep_convert<<<NPTS / 4, 256, 0, stream>>>(obs, obsb, sq);
    thresh_pass<<<128 * 4, 256, 0, stream>>>(obsb, sq, Trow4);
    knn_main<<<128 * NSPLIT, 256, 0, stream>>>(obsb, sq, Trow4, cand);
    merge_out<<<NPTS / 256, 256, 0, stream>>>(cand, out);
}

// Round 11
// 399.880 us; speedup vs baseline: 2.1369x; 1.3011x over previous
//
#include <hip/hip_runtime.h>
#include <math.h>

// ---- problem constants (fixed shapes) ----
#define NPTS 16384
#define DIM  512
#define KSEL 11                   // K+1 smallest incl. self; min dropped at the end
#define NSPLIT 4
#define CPS   (NPTS / NSPLIT)     // 4096 columns per split
#define BM    128                 // rows per block (4 waves x 32 rows)
#define BN    32                  // columns staged per iteration (32 KB)
#define MITERS (CPS / BN)         // 128 main iterations per split
#define TITERS 32                 // threshold pass: 1024 cols per quarter-sample
#define STRIPB 16384              // bytes per 16-row/col fragment-major strip
#define CAP   48                  // appended candidates per (row, split)

typedef __attribute__((ext_vector_type(4))) float f32x4;
typedef __attribute__((ext_vector_type(8))) short s16x8;

__device__ __forceinline__ unsigned short f2bf(float f) {
    unsigned int x = __float_as_uint(f);
    return (unsigned short)((x + 0x7FFFu + ((x >> 16) & 1u)) >> 16);
}

__device__ __forceinline__ void gload_lds16(const void* g, void* l) {
    __builtin_amdgcn_global_load_lds(
        (const __attribute__((address_space(1))) void*)g,
        (__attribute__((address_space(3))) void*)l, 16, 0, 0);
}

// pin a loaded value: opaque -> compiler cannot rematerialize
__device__ __forceinline__ void pinreg(s16x8& v) { asm volatile("" : "+v"(v)); }
__device__ __forceinline__ void pinf(float& v)   { asm volatile("" : "+v"(v)); }

// scalar exact top-KSEL (smallest) scan over v[0..n), n >= KSEL; returns 11th smallest
__device__ __forceinline__ float topk_scan(const float* v, int n, float* a) {
    #pragma unroll
    for (int p = 0; p < KSEL; ++p) a[p] = v[p];
    float mx = a[0];
    #pragma unroll
    for (int p = 1; p < KSEL; ++p) mx = fmaxf(mx, a[p]);
    for (int i = KSEL; i < n; ++i) {
        const float x = v[i];
        if (x < mx) {
            bool done = false;
            #pragma unroll
            for (int p = 0; p < KSEL; ++p) {
                const bool rep = (!done) && (a[p] == mx);
                a[p] = rep ? x : a[p];
                done = done || rep;
            }
            mx = a[0];
            #pragma unroll
            for (int p = 1; p < KSEL; ++p) mx = fmaxf(mx, a[p]);
        }
    }
    return mx;
}

// ---- kernel 1: fused fp32->bf16 convert into fragment-major layout + ||x_i||^2
//   byte(row,k) = (row>>4)*16384 + (k>>5)*1024 + ((k>>3)&3)*256 + (row&15)*16 + (k&7)*2
__global__ void prep_convert(const float* __restrict__ obs, char* __restrict__ obsb,
                             float* __restrict__ sq) {
    const int wv = threadIdx.x >> 6, ln = threadIdx.x & 63;
    const int row = blockIdx.x * 4 + wv;
    const float4* s = (const float4*)(obs + (unsigned long)row * DIM + ln * 8);
    const float4 a = s[0], b = s[1];
    uint4 o;
    o.x = (unsigned int)f2bf(a.x) | ((unsigned int)f2bf(a.y) << 16);
    o.y = (unsigned int)f2bf(a.z) | ((unsigned int)f2bf(a.w) << 16);
    o.z = (unsigned int)f2bf(b.x) | ((unsigned int)f2bf(b.y) << 16);
    o.w = (unsigned int)f2bf(b.z) | ((unsigned int)f2bf(b.w) << 16);
    *(uint4*)(obsb + (unsigned long)(row >> 4) * STRIPB + (ln >> 2) * 1024
              + (ln & 3) * 256 + (row & 15) * 16) = o;
    float ss = a.x*a.x + a.y*a.y + a.z*a.z + a.w*a.w
             + b.x*b.x + b.y*b.y + b.z*b.z + b.w*b.w;
    #pragma unroll
    for (int off = 32; off; off >>= 1) ss += __shfl_xor(ss, off);
    if (ln == 0) sq[row] = ss;
}

// ---- shared 2-phase double-buffer GEMM macros (R3 cadence, R7 linear layout) ----
#define STAGE(BUF, CITER) do {                                                  \
        const char* gs_ = obsb + (unsigned long)((C0 >> 4) + 2 * (CITER)) * STRIPB \
                          + wv * 8192 + ln * 16;                                \
        char* lb_ = &Braw[BUF][0] + wv * 8192;                                  \
        _Pragma("unroll")                                                       \
        for (int r_ = 0; r_ < 8; ++r_)                                          \
            gload_lds16(gs_ + r_ * 1024, lb_ + r_ * 1024);                      \
    } while (0)

#define GEMM_BODY(CUR, CITER)                                                   \
        const char* bp = &Braw[CUR][0];                                         \
        f32x4 acc[2][2] = {{{0.f,0.f,0.f,0.f},{0.f,0.f,0.f,0.f}},               \
                           {{0.f,0.f,0.f,0.f},{0.f,0.f,0.f,0.f}}};              \
        _Pragma("unroll")                                                       \
        for (int cg = 0; cg < 2; ++cg) {                                        \
            _Pragma("unroll")                                                   \
            for (int t = 0; t < 16; ++t) {                                      \
                const s16x8 b = *(const s16x8*)(bp + cg * STRIPB + t * 1024 + lfrag); \
                acc[0][cg] = __builtin_amdgcn_mfma_f32_16x16x32_bf16(b, afrag[0][t], acc[0][cg], 0, 0, 0); \
                acc[1][cg] = __builtin_amdgcn_mfma_f32_16x16x32_bf16(b, afrag[1][t], acc[1][cg], 0, 0, 0); \
            }                                                                   \
        }                                                                       \
        f32x4 sqv[2];                                                           \
        sqv[0] = *(const f32x4*)(sq + C0 + (CITER) * BN + kc * 4);              \
        sqv[1] = *(const f32x4*)(sq + C0 + (CITER) * BN + 16 + kc * 4);

#define DIST(S, CG, R) fmaf(-2.0f, acc[S][CG][R], sqr[S] + sqv[CG][R])

#define LOAD_AFRAG() do {                                                       \
        _Pragma("unroll")                                                       \
        for (int s = 0; s < 2; ++s) {                                           \
            const unsigned long sbase = (unsigned long)((R0 >> 4) + wv * 2 + s) * STRIPB; \
            _Pragma("unroll")                                                   \
            for (int t = 0; t < 16; ++t) {                                      \
                afrag[s][t] = *(const s16x8*)(obsb + sbase + t * 1024 + lfrag); \
                pinreg(afrag[s][t]);                                            \
            }                                                                   \
            sqr[s] = sq[wrow0 + s * 16 + lr];                                   \
            pinf(sqr[s]);                                                       \
        }                                                                       \
    } while (0)

// ---- kernel 2: threshold pass — per (row-tile, quarter) the 11 smallest of 32
//   slot-minima over 1024 distinct cols (each an ACTUAL distance). Written to Tv.
__global__ __launch_bounds__(256, 2) void thresh_pass(
    const char* __restrict__ obsb, const float* __restrict__ sq,
    float* __restrict__ Tv)
{
    __shared__ __align__(16) char Braw[2][BN * 1024];   // 64 KB double buffer

    const int tid = threadIdx.x;
    const int wv = tid >> 6, ln = tid & 63;
    const int q  = blockIdx.x >> 7;          // quarter-sample 0..3
    const int rt = blockIdx.x & 127;         // row tile 0..127
    const int R0 = rt * BM;
    const int C0 = q * CPS;                  // sample = first 1024 cols of split q
    const int wrow0 = R0 + wv * 32;
    const int lr = ln & 15;
    const int kc = ln >> 4;
    const int lfrag = kc * 256 + lr * 16;

    s16x8 afrag[2][16];
    float sqr[2];
    LOAD_AFRAG();

    float segmin[2][8];
    #pragma unroll
    for (int s = 0; s < 2; ++s)
        #pragma unroll
        for (int p = 0; p < 8; ++p) segmin[s][p] = __builtin_inff();

    STAGE(0, 0);
    __syncthreads();
    #pragma unroll 2
    for (int it = 0; it < TITERS; ++it) {
        const int cur = it & 1;
        if (it + 1 < TITERS) STAGE(cur ^ 1, it + 1);
        GEMM_BODY(cur, it);
        #pragma unroll
        for (int s = 0; s < 2; ++s)
            #pragma unroll
            for (int cg = 0; cg < 2; ++cg)
                #pragma unroll
                for (int r = 0; r < 4; ++r)
                    segmin[s][cg * 4 + r] = fminf(segmin[s][cg * 4 + r], DIST(s, cg, r));
        __syncthreads();
    }

    // gather 32 slot-minima per row (stride 33) -> 11 smallest -> Tv[row][q][11]
    float* mins = (float*)&Braw[0][0];               // [BM][33]
    #pragma unroll
    for (int s = 0; s < 2; ++s)
        #pragma unroll
        for (int p = 0; p < 8; ++p)
            mins[(wv * 32 + s * 16 + lr) * 33 + kc * 8 + p] = segmin[s][p];
    __syncthreads();
    if (tid < BM) {
        float a[KSEL];
        topk_scan(mins + tid * 33, 32, a);
        #pragma unroll
        for (int p = 0; p < KSEL; ++p)
            Tv[(unsigned long)(R0 + tid) * (4 * KSEL) + q * KSEL + p] = a[p];
    }
}

// ---- kernel 3: T[row] = 11th smallest of the 44 quarter values
//   (= 11th smallest of 128 slot-minima over 4096 distinct cols; each is an actual
//    distance => provable upper bound of the row's true 11th smallest.)
__global__ void tmerge(const float* __restrict__ Tv, float* __restrict__ T) {
    const int row = blockIdx.x * 256 + threadIdx.x;
    float a[KSEL];
    T[row] = topk_scan(Tv + (unsigned long)row * (4 * KSEL), 4 * KSEL, a);
}

// ---- kernel 4: main pass — GEMM + rare predicated append (LDS counter, global vals)
__global__ __launch_bounds__(256, 2) void knn_main(
    const char* __restrict__ obsb, const float* __restrict__ sq,
    const float* __restrict__ T, int* __restrict__ cnt,
    float* __restrict__ vals)
{
    __shared__ __align__(16) char Braw[2][BN * 1024];   // 64 KB double buffer
    __shared__ unsigned lcnt[BM];

    const int tid = threadIdx.x;
    const int wv = tid >> 6, ln = tid & 63;
    const int sp = blockIdx.x >> 7;          // split 0..3
    const int rt = blockIdx.x & 127;         // row tile 0..127
    const int R0 = rt * BM;
    const int C0 = sp * CPS;
    const int wrow0 = R0 + wv * 32;
    const int lr = ln & 15;
    const int kc = ln >> 4;
    const int lfrag = kc * 256 + lr * 16;

    if (tid < BM) lcnt[tid] = 0u;

    s16x8 afrag[2][16];
    float sqr[2];
    LOAD_AFRAG();

    unsigned lrow[2]; float tval[2]; float* vbase[2];
    #pragma unroll
    for (int s = 0; s < 2; ++s) {
        const int row = wrow0 + s * 16 + lr;
        lrow[s]  = wv * 32 + s * 16 + lr;
        tval[s]  = T[row];
        pinf(tval[s]);
        vbase[s] = vals + ((unsigned long)row * 4 + sp) * CAP;
    }

    // exact gate: v <= T (recompute is bit-identical to thresh_pass's defining values)
#define APP(S, VV) do {                                                         \
        const float v_ = (VV);                                                  \
        if (v_ <= tval[S]) {                                                    \
            const unsigned i_ = atomicAdd(&lcnt[lrow[S]], 1u);                  \
            if (i_ < CAP) vbase[S][i_] = v_;                                    \
        }                                                                       \
    } while (0)

    STAGE(0, 0);
    __syncthreads();
    #pragma unroll 2
    for (int it = 0; it < MITERS; ++it) {
        const int cur = it & 1;
        if (it + 1 < MITERS) STAGE(cur ^ 1, it + 1);
        GEMM_BODY(cur, it);
        #pragma unroll
        for (int s = 0; s < 2; ++s) {
            APP(s, DIST(s, 0, 0)); APP(s, DIST(s, 0, 1));
            APP(s, DIST(s, 0, 2)); APP(s, DIST(s, 0, 3));
            APP(s, DIST(s, 1, 0)); APP(s, DIST(s, 1, 1));
            APP(s, DIST(s, 1, 2)); APP(s, DIST(s, 1, 3));
        }
        __syncthreads();
    }

    if (tid < BM) {
        const unsigned c = lcnt[tid];
        cnt[(unsigned long)(R0 + tid) * 4 + sp] = (int)(c < CAP ? c : CAP);
    }
}

// ---- kernel 5: per row, exact top-11 of appended candidates -> output
__global__ void merge_out(const int* __restrict__ cnt, const float* __restrict__ vals,
                          float* __restrict__ out) {
    const int row = blockIdx.x * 256 + threadIdx.x;
    float arr[KSEL];
    #pragma unroll
    for (int p = 0; p < KSEL; ++p) arr[p] = __builtin_inff();
    float mx = __builtin_inff();
    for (int q = 0; q < 4; ++q) {
        const int n = min(cnt[(unsigned long)row * 4 + q], CAP);
        const float* base = vals + ((unsigned long)row * 4 + q) * CAP;
        for (int i = 0; i < n; ++i) {
            const float x = base[i];
            if (x < mx) {
                bool done = false;
                #pragma unroll
                for (int p = 0; p < KSEL; ++p) {
                    const bool rep = (!done) && (arr[p] == mx);
                    arr[p] = rep ? x : arr[p];
                    done = done || rep;
                }
                mx = arr[0];
                #pragma unroll
                for (int p = 1; p < KSEL; ++p) mx = fmaxf(mx, arr[p]);
            }
        }
    }
    float mn = arr[0];
    #pragma unroll
    for (int p = 1; p < KSEL; ++p) mn = fminf(mn, arr[p]);
    float ssum = 0.f;
    #pragma unroll
    for (int p = 0; p < KSEL; ++p) ssum += sqrtf(fmaxf(arr[p], 0.f));
    out[row] = log1pf((ssum - sqrtf(fmaxf(mn, 0.f))) * 0.1f);
}

extern "C" void kernel_launch(void* const* d_in, const int* in_sizes, int n_in,
                              void* d_out, int out_size, void* d_ws, size_t ws_size,
                              hipStream_t stream) {
    const float* obs = (const float*)d_in[0];
    float* out = (float*)d_out;
    char* ws = (char*)d_ws;

    char*  obsb = ws;                                        // 16 MB fragment-major bf16
    float* sq   = (float*)(ws + (size_t)NPTS * 1024);        // 64 KB
    float* T    = sq + NPTS;                                 // 64 KB
    int*   cnt  = (int*)(T + NPTS);                          // 256 KB
    float* vals = (float*)(cnt + NPTS * 4);                  // 12 MB (CAP=48)
    float* Tv   = vals;   // aliased: Tv (2.75 MB) consumed by tmerge BEFORE
                          // knn_main writes vals (stream-ordered, no overlap in time)

    prep_convert<<<NPTS / 4, 256, 0, stream>>>(obs, obsb, sq);
    thresh_pass<<<128 * 4, 256, 0, stream>>>(obsb, sq, Tv);
    tmerge<<<NPTS / 256, 256, 0, stream>>>(Tv, T);
    knn_main<<<128 * NSPLIT, 256, 0, stream>>>(obsb, sq, T, cnt, vals);
    merge_out<<<NPTS / 256, 256, 0, stream>>>(cnt, vals, out);
}

// Round 12
// 324.237 us; speedup vs baseline: 2.6354x; 1.2333x over previous
//
#include <hip/hip_runtime.h>
#include <math.h>

// ---- problem constants (fixed shapes) ----
#define NPTS 16384
#define DIM  512
#define KSEL 11                   // K+1 smallest incl. self; min dropped at the end
#define NSPLIT 4
#define CPS   (NPTS / NSPLIT)     // 4096 columns per split
#define BM    128                 // rows per block (4 waves x 32 rows)
#define BN    64                  // columns staged per iteration (32 KB in i8)
#define MITERS (CPS / BN)         // 64 main iterations per split
#define TITERS 16                 // threshold pass: 1024 cols per quarter-sample
#define STRIPB 8192               // bytes per 16-row/col fragment-major strip (i8)
#define CAP   48                  // appended candidates per (row, split)
#define QS    22.0f               // quantization scale: x_i8 = clamp(rint(22 x), +-127)

typedef __attribute__((ext_vector_type(4))) int  i32x4;
typedef __attribute__((ext_vector_type(2))) long l64x2;

__device__ __forceinline__ void gload_lds16(const void* g, void* l) {
    __builtin_amdgcn_global_load_lds(
        (const __attribute__((address_space(1))) void*)g,
        (__attribute__((address_space(3))) void*)l, 16, 0, 0);
}

// pin a loaded value: opaque -> compiler cannot rematerialize / reorder its wait
__device__ __forceinline__ void pinreg(l64x2& v) { asm volatile("" : "+v"(v)); }
__device__ __forceinline__ void pini(int& v)     { asm volatile("" : "+v"(v)); }

// exact KSEL-smallest scan over ints v[0..n), n >= KSEL; a[] gets them; returns the KSEL-th
__device__ __forceinline__ int topk_scan_i(const int* v, int n, int* a) {
    #pragma unroll
    for (int p = 0; p < KSEL; ++p) a[p] = v[p];
    int mx = a[0];
    #pragma unroll
    for (int p = 1; p < KSEL; ++p) mx = max(mx, a[p]);
    for (int i = KSEL; i < n; ++i) {
        const int x = v[i];
        if (x < mx) {
            bool done = false;
            #pragma unroll
            for (int p = 0; p < KSEL; ++p) {
                const bool rep = (!done) && (a[p] == mx);
                a[p] = rep ? x : a[p];
                done = done || rep;
            }
            mx = a[0];
            #pragma unroll
            for (int p = 1; p < KSEL; ++p) mx = max(mx, a[p]);
        }
    }
    return mx;
}

// ---- kernel 1: fp32 -> i8 quantize into fragment-major layout + sqi[i] = ||xi8||^2
//   k-mapping: th=k>>6, t_odd=(k>>5)&1, kc=(k>>3)&3, j=k&7
//   byte(row,k) = (row>>4)*8192 + th*1024 + kc*256 + (row&15)*16 + t_odd*8 + j
//   (one ds_read_b128 per lane yields the t=2th AND t=2th+1 MFMA fragments)
__global__ void prep_convert(const float* __restrict__ obs, char* __restrict__ obsb,
                             int* __restrict__ sqi) {
    const int wv = threadIdx.x >> 6, ln = threadIdx.x & 63;
    const int row = blockIdx.x * 4 + wv;
    const float4* s = (const float4*)(obs + (unsigned long)row * DIM + ln * 8);
    const float4 a = s[0], b = s[1];
    float xs[8] = {a.x, a.y, a.z, a.w, b.x, b.y, b.z, b.w};
    unsigned long u = 0ul;
    int ssum = 0;
    #pragma unroll
    for (int j = 0; j < 8; ++j) {
        const int q = __float2int_rn(fminf(fmaxf(xs[j] * QS, -127.f), 127.f));
        ssum += q * q;
        u |= ((unsigned long)((unsigned)q & 0xffu)) << (8 * j);
    }
    // lane ln owns k0 = ln*8: th=ln>>3, kc=ln&3, t_odd=(ln>>2)&1
    *(unsigned long*)(obsb + (unsigned long)(row >> 4) * STRIPB + (ln >> 3) * 1024
                      + (ln & 3) * 256 + (row & 15) * 16 + ((ln >> 2) & 1) * 8) = u;
    #pragma unroll
    for (int off = 32; off; off >>= 1) ssum += __shfl_xor(ssum, off);
    if (ln == 0) sqi[row] = ssum;
}

// ---- shared 2-phase double-buffer GEMM macros (proven cadence, i8 / BN=64) ----
// tile = 64 cols = 4 strips = 32 KB; wave wv stages strip wv (8 x 1KB lane-linear)
#define STAGE(BUF, CITER) do {                                                  \
        const char* gs_ = obsb + (unsigned long)((C0 >> 4) + 4 * (CITER)) * STRIPB \
                          + wv * 8192 + ln * 16;                                \
        char* lb_ = &Braw[BUF][0] + wv * 8192;                                  \
        _Pragma("unroll")                                                       \
        for (int r_ = 0; r_ < 8; ++r_)                                          \
            gload_lds16(gs_ + r_ * 1024, lb_ + r_ * 1024);                      \
    } while (0)

// per wave-iter: 32 ds_read_b128 + 128 MFMA i8 (K=512 via 16 t-steps x 4 col-groups)
#define GEMM_BODY(CUR, CITER)                                                   \
        const char* bp = &Braw[CUR][0];                                         \
        i32x4 acc[2][4] = {{{0,0,0,0},{0,0,0,0},{0,0,0,0},{0,0,0,0}},           \
                           {{0,0,0,0},{0,0,0,0},{0,0,0,0},{0,0,0,0}}};          \
        _Pragma("unroll")                                                       \
        for (int cg = 0; cg < 4; ++cg) {                                        \
            _Pragma("unroll")                                                   \
            for (int th = 0; th < 8; ++th) {                                    \
                const l64x2 b = *(const l64x2*)(bp + cg * STRIPB + th * 1024 + lfrag); \
                acc[0][cg] = __builtin_amdgcn_mfma_i32_16x16x32_i8(b[0], afrag[0][th][0], acc[0][cg], 0, 0, 0); \
                acc[1][cg] = __builtin_amdgcn_mfma_i32_16x16x32_i8(b[0], afrag[1][th][0], acc[1][cg], 0, 0, 0); \
                acc[0][cg] = __builtin_amdgcn_mfma_i32_16x16x32_i8(b[1], afrag[0][th][1], acc[0][cg], 0, 0, 0); \
                acc[1][cg] = __builtin_amdgcn_mfma_i32_16x16x32_i8(b[1], afrag[1][th][1], acc[1][cg], 0, 0, 0); \
            }                                                                   \
        }                                                                       \
        i32x4 sqv[4];                                                           \
        _Pragma("unroll")                                                       \
        for (int cg_ = 0; cg_ < 4; ++cg_)                                       \
            sqv[cg_] = *(const i32x4*)(sqi + C0 + (CITER) * BN + cg_ * 16 + kc * 4);

// exact integer distance: d2i = |xr|^2 + |xc|^2 - 2 xr.xc  (fits int32: < 3.4e7)
#define DIST(S, CG, R) (sqr[S] + sqv[CG][R] - 2 * acc[S][CG][R])

#define LOAD_AFRAG() do {                                                       \
        _Pragma("unroll")                                                       \
        for (int s = 0; s < 2; ++s) {                                           \
            const unsigned long sbase = (unsigned long)((R0 >> 4) + wv * 2 + s) * STRIPB; \
            _Pragma("unroll")                                                   \
            for (int th = 0; th < 8; ++th) {                                    \
                afrag[s][th] = *(const l64x2*)(obsb + sbase + th * 1024 + lfrag); \
                pinreg(afrag[s][th]);                                           \
            }                                                                   \
            sqr[s] = sqi[wrow0 + s * 16 + lr];                                  \
            pini(sqr[s]);                                                       \
        }                                                                       \
    } while (0)

// ---- kernel 2: threshold pass — per (row-tile, quarter) the 11 smallest of 64
//   slot-minima over 1024 distinct cols (each an ACTUAL int distance) -> Tv
__global__ __launch_bounds__(256, 2) void thresh_pass(
    const char* __restrict__ obsb, const int* __restrict__ sqi,
    int* __restrict__ Tv)
{
    __shared__ __align__(16) char Braw[2][BN * 512];    // 64 KB double buffer

    const int tid = threadIdx.x;
    const int wv = tid >> 6, ln = tid & 63;
    const int q  = blockIdx.x >> 7;          // quarter-sample 0..3
    const int rt = blockIdx.x & 127;         // row tile 0..127
    const int R0 = rt * BM;
    const int C0 = q * CPS;                  // sample = first 1024 cols of split q
    const int wrow0 = R0 + wv * 32;
    const int lr = ln & 15;
    const int kc = ln >> 4;
    const int lfrag = kc * 256 + lr * 16;

    l64x2 afrag[2][8];
    int sqr[2];
    LOAD_AFRAG();

    int segmin[2][16];
    #pragma unroll
    for (int s = 0; s < 2; ++s)
        #pragma unroll
        for (int p = 0; p < 16; ++p) segmin[s][p] = 0x7FFFFFFF;

    STAGE(0, 0);
    __syncthreads();
    #pragma unroll 2
    for (int it = 0; it < TITERS; ++it) {
        const int cur = it & 1;
        if (it + 1 < TITERS) STAGE(cur ^ 1, it + 1);
        GEMM_BODY(cur, it);
        #pragma unroll
        for (int s = 0; s < 2; ++s)
            #pragma unroll
            for (int cg = 0; cg < 4; ++cg)
                #pragma unroll
                for (int r = 0; r < 4; ++r)
                    segmin[s][cg * 4 + r] = min(segmin[s][cg * 4 + r], DIST(s, cg, r));
        __syncthreads();
    }

    // gather 64 slot-minima per row (stride 65) -> 11 smallest -> Tv[row][q][11]
    int* mins = (int*)&Braw[0][0];               // [BM][65] = 33 KB
    #pragma unroll
    for (int s = 0; s < 2; ++s)
        #pragma unroll
        for (int p = 0; p < 16; ++p)
            mins[(wv * 32 + s * 16 + lr) * 65 + kc * 16 + p] = segmin[s][p];
    __syncthreads();
    if (tid < BM) {
        int a[KSEL];
        topk_scan_i(mins + tid * 65, 64, a);
        #pragma unroll
        for (int p = 0; p < KSEL; ++p)
            Tv[(unsigned long)(R0 + tid) * (4 * KSEL) + q * KSEL + p] = a[p];
    }
}

// ---- kernel 3: T[row] = 11th smallest of the 44 quarter values
//   (44 actual distances at distinct columns => provable upper bound of true 11th)
__global__ void tmerge(const int* __restrict__ Tv, int* __restrict__ T) {
    const int row = blockIdx.x * 256 + threadIdx.x;
    int a[KSEL];
    T[row] = topk_scan_i(Tv + (unsigned long)row * (4 * KSEL), 4 * KSEL, a);
}

// ---- kernel 4: main pass — GEMM + rare predicated append (LDS counter, global vals)
__global__ __launch_bounds__(256, 2) void knn_main(
    const char* __restrict__ obsb, const int* __restrict__ sqi,
    const int* __restrict__ T, int* __restrict__ cnt,
    int* __restrict__ vals)
{
    __shared__ __align__(16) char Braw[2][BN * 512];    // 64 KB double buffer
    __shared__ unsigned lcnt[BM];

    const int tid = threadIdx.x;
    const int wv = tid >> 6, ln = tid & 63;
    const int sp = blockIdx.x >> 7;          // split 0..3
    const int rt = blockIdx.x & 127;         // row tile 0..127
    const int R0 = rt * BM;
    const int C0 = sp * CPS;
    const int wrow0 = R0 + wv * 32;
    const int lr = ln & 15;
    const int kc = ln >> 4;
    const int lfrag = kc * 256 + lr * 16;

    if (tid < BM) lcnt[tid] = 0u;

    l64x2 afrag[2][8];
    int sqr[2];
    LOAD_AFRAG();

    unsigned lrow[2]; int tval[2]; int* vbase[2];
    #pragma unroll
    for (int s = 0; s < 2; ++s) {
        const int row = wrow0 + s * 16 + lr;
        lrow[s]  = wv * 32 + s * 16 + lr;
        tval[s]  = T[row];                   // exact int gate, no slack needed
        pini(tval[s]);
        vbase[s] = vals + ((unsigned long)row * 4 + sp) * CAP;
    }

#define APP(S, VV) do {                                                         \
        const int v_ = (VV);                                                    \
        if (v_ <= tval[S]) {                                                    \
            const unsigned i_ = atomicAdd(&lcnt[lrow[S]], 1u);                  \
            if (i_ < CAP) vbase[S][i_] = v_;                                    \
        }                                                                       \
    } while (0)

    STAGE(0, 0);
    __syncthreads();
    #pragma unroll 2
    for (int it = 0; it < MITERS; ++it) {
        const int cur = it & 1;
        if (it + 1 < MITERS) STAGE(cur ^ 1, it + 1);
        GEMM_BODY(cur, it);
        #pragma unroll
        for (int s = 0; s < 2; ++s) {
            #pragma unroll
            for (int cg = 0; cg < 4; ++cg) {
                APP(s, DIST(s, cg, 0)); APP(s, DIST(s, cg, 1));
                APP(s, DIST(s, cg, 2)); APP(s, DIST(s, cg, 3));
            }
        }
        __syncthreads();
    }

    if (tid < BM) {
        const unsigned c = lcnt[tid];
        cnt[(unsigned long)(R0 + tid) * 4 + sp] = (int)(c < CAP ? c : CAP);
    }
}

// ---- kernel 5: per row, exact top-11 of appended int candidates -> output
__global__ void merge_out(const int* __restrict__ cnt, const int* __restrict__ vals,
                          float* __restrict__ out) {
    const int row = blockIdx.x * 256 + threadIdx.x;
    int arr[KSEL];
    #pragma unroll
    for (int p = 0; p < KSEL; ++p) arr[p] = 0x7FFFFFFF;
    int mx = 0x7FFFFFFF;
    for (int q = 0; q < 4; ++q) {
        const int n = min(cnt[(unsigned long)row * 4 + q], CAP);
        const int* base = vals + ((unsigned long)row * 4 + q) * CAP;
        for (int i = 0; i < n; ++i) {
            const int x = base[i];
            if (x < mx) {
                bool done = false;
                #pragma unroll
                for (int p = 0; p < KSEL; ++p) {
                    const bool rep = (!done) && (arr[p] == mx);
                    arr[p] = rep ? x : arr[p];
                    done = done || rep;
                }
                mx = arr[0];
                #pragma unroll
                for (int p = 1; p < KSEL; ++p) mx = max(mx, arr[p]);
            }
        }
    }
    int mn = arr[0];
    #pragma unroll
    for (int p = 1; p < KSEL; ++p) mn = min(mn, arr[p]);
    float ssum = 0.f;
    #pragma unroll
    for (int p = 0; p < KSEL; ++p) ssum += sqrtf((float)max(arr[p], 0));
    const float smn = sqrtf((float)max(mn, 0));
    out[row] = log1pf((ssum - smn) * (0.1f / QS));   // r = sqrt(d2i)/QS; mean of 10
}

extern "C" void kernel_launch(void* const* d_in, const int* in_sizes, int n_in,
                              void* d_out, int out_size, void* d_ws, size_t ws_size,
                              hipStream_t stream) {
    const float* obs = (const float*)d_in[0];
    float* out = (float*)d_out;
    char* ws = (char*)d_ws;

    char* obsb = ws;                                         // 8 MB fragment-major i8
    int*  sqi  = (int*)(ws + (size_t)NPTS * 512);            // 64 KB
    int*  T    = sqi + NPTS;                                 // 64 KB
    int*  cnt  = T + NPTS;                                   // 256 KB
    int*  vals = cnt + NPTS * 4;                             // 12 MB (CAP=48)
    int*  Tv   = vals;   // aliased: Tv (2.75 MB) is consumed by tmerge BEFORE
                         // knn_main writes vals (stream-ordered, no overlap)

    prep_convert<<<NPTS / 4, 256, 0, stream>>>(obs, obsb, sqi);
    thresh_pass<<<128 * 4, 256, 0, stream>>>(obsb, sqi, Tv);
    tmerge<<<NPTS / 256, 256, 0, stream>>>(Tv, T);
    knn_main<<<128 * NSPLIT, 256, 0, stream>>>(obsb, sqi, T, cnt, vals);
    merge_out<<<NPTS / 256, 256, 0, stream>>>(cnt, vals, out);
}

// Round 13
// 285.013 us; speedup vs baseline: 2.9980x; 1.1376x over previous
//
#include <hip/hip_runtime.h>
#include <math.h>

// ---- problem constants (fixed shapes) ----
#define NPTS 16384
#define DIM  512
#define KSEL 11                   // K+1 smallest incl. self; min dropped at the end
#define NSPLIT 4
#define CPS   (NPTS / NSPLIT)     // 4096 columns per split
#define BM    128                 // rows per block (4 waves x 32 rows)
#define BN    64                  // columns staged per iteration (32 KB in i8)
#define MITERS (CPS / BN)         // 64 main iterations per split
#define TITERS 16                 // threshold pass: 1024 cols per quarter-sample
#define STRIPB 8192               // bytes per 16-row/col fragment-major strip (i8)
#define CAP   48                  // appended candidates per (row, split)
#define QS    22.0f               // quantization scale: x_i8 = clamp(rint(22 x), +-127)

typedef __attribute__((ext_vector_type(4))) int i32x4;

__device__ __forceinline__ void gload_lds16(const void* g, void* l) {
    __builtin_amdgcn_global_load_lds(
        (const __attribute__((address_space(1))) void*)g,
        (__attribute__((address_space(3))) void*)l, 16, 0, 0);
}

// pin a loaded value: opaque -> compiler cannot rematerialize / reorder its wait
__device__ __forceinline__ void pinreg(i32x4& v) { asm volatile("" : "+v"(v)); }
__device__ __forceinline__ void pini(int& v)     { asm volatile("" : "+v"(v)); }

// exact KSEL-smallest scan over ints v[0..n), n >= KSEL; a[] gets them; returns the KSEL-th
__device__ __forceinline__ int topk_scan_i(const int* v, int n, int* a) {
    #pragma unroll
    for (int p = 0; p < KSEL; ++p) a[p] = v[p];
    int mx = a[0];
    #pragma unroll
    for (int p = 1; p < KSEL; ++p) mx = max(mx, a[p]);
    for (int i = KSEL; i < n; ++i) {
        const int x = v[i];
        if (x < mx) {
            bool done = false;
            #pragma unroll
            for (int p = 0; p < KSEL; ++p) {
                const bool rep = (!done) && (a[p] == mx);
                a[p] = rep ? x : a[p];
                done = done || rep;
            }
            mx = a[0];
            #pragma unroll
            for (int p = 1; p < KSEL; ++p) mx = max(mx, a[p]);
        }
    }
    return mx;
}

// ---- kernel 1: fp32 -> i8 quantize into K=64 fragment-major layout + sqi = ||xi8||^2
//   byte(row,k) = (row>>4)*8192 + (k>>6)*1024 + ((k>>4)&3)*256 + (row&15)*16 + (k&15)
//   (one ds_read_b128 per lane = one complete 16x16x64 fragment k-slice)
__global__ void prep_convert(const float* __restrict__ obs, char* __restrict__ obsb,
                             int* __restrict__ sqi) {
    const int wv = threadIdx.x >> 6, ln = threadIdx.x & 63;
    const int row = blockIdx.x * 4 + wv;
    const float4* s = (const float4*)(obs + (unsigned long)row * DIM + ln * 8);
    const float4 a = s[0], b = s[1];
    float xs[8] = {a.x, a.y, a.z, a.w, b.x, b.y, b.z, b.w};
    unsigned long u = 0ul;
    int ssum = 0;
    #pragma unroll
    for (int j = 0; j < 8; ++j) {
        const int q = __float2int_rn(fminf(fmaxf(xs[j] * QS, -127.f), 127.f));
        ssum += q * q;
        u |= ((unsigned long)((unsigned)q & 0xffu)) << (8 * j);
    }
    // lane ln owns k0 = ln*8 (8 bytes): t=ln>>3, kc=(ln>>1)&3, half=ln&1
    *(unsigned long*)(obsb + (unsigned long)(row >> 4) * STRIPB + (ln >> 3) * 1024
                      + ((ln >> 1) & 3) * 256 + (row & 15) * 16 + (ln & 1) * 8) = u;
    #pragma unroll
    for (int off = 32; off; off >>= 1) ssum += __shfl_xor(ssum, off);
    if (ln == 0) sqi[row] = ssum;
}

// ---- shared 2-phase double-buffer GEMM macros (proven cadence, i8 K=64 / BN=64) ----
// tile = 64 cols = 4 strips = 32 KB; wave wv stages strip wv (8 x 1KB lane-linear)
#define STAGE(BUF, CITER) do {                                                  \
        const char* gs_ = obsb + (unsigned long)((C0 >> 4) + 4 * (CITER)) * STRIPB \
                          + wv * 8192 + ln * 16;                                \
        char* lb_ = &Braw[BUF][0] + wv * 8192;                                  \
        _Pragma("unroll")                                                       \
        for (int r_ = 0; r_ < 8; ++r_)                                          \
            gload_lds16(gs_ + r_ * 1024, lb_ + r_ * 1024);                      \
    } while (0)

// per wave-iter: 32 ds_read_b128 + 64 MFMA i8 K=64 (K=512 via 8 t-steps x 4 col-groups)
#define GEMM_BODY(CUR, CITER)                                                   \
        const char* bp = &Braw[CUR][0];                                         \
        i32x4 acc[2][4] = {{{0,0,0,0},{0,0,0,0},{0,0,0,0},{0,0,0,0}},           \
                           {{0,0,0,0},{0,0,0,0},{0,0,0,0},{0,0,0,0}}};          \
        _Pragma("unroll")                                                       \
        for (int cg = 0; cg < 4; ++cg) {                                        \
            _Pragma("unroll")                                                   \
            for (int t = 0; t < 8; ++t) {                                       \
                const i32x4 b = *(const i32x4*)(bp + cg * STRIPB + t * 1024 + lfrag); \
                acc[0][cg] = __builtin_amdgcn_mfma_i32_16x16x64_i8(b, afrag[0][t], acc[0][cg], 0, 0, 0); \
                acc[1][cg] = __builtin_amdgcn_mfma_i32_16x16x64_i8(b, afrag[1][t], acc[1][cg], 0, 0, 0); \
            }                                                                   \
        }                                                                       \
        i32x4 sqv[4];                                                           \
        _Pragma("unroll")                                                       \
        for (int cg_ = 0; cg_ < 4; ++cg_)                                       \
            sqv[cg_] = *(const i32x4*)(sqi + C0 + (CITER) * BN + cg_ * 16 + kc * 4);

// exact integer distance: d2i = |xr|^2 + |xc|^2 - 2 xr.xc  (fits int32: < 3.4e7)
#define DIST(S, CG, R) (sqr[S] + sqv[CG][R] - 2 * acc[S][CG][R])

#define LOAD_AFRAG() do {                                                       \
        _Pragma("unroll")                                                       \
        for (int s = 0; s < 2; ++s) {                                           \
            const unsigned long sbase = (unsigned long)((R0 >> 4) + wv * 2 + s) * STRIPB; \
            _Pragma("unroll")                                                   \
            for (int t = 0; t < 8; ++t) {                                       \
                afrag[s][t] = *(const i32x4*)(obsb + sbase + t * 1024 + lfrag); \
                pinreg(afrag[s][t]);                                            \
            }                                                                   \
            sqr[s] = sqi[wrow0 + s * 16 + lr];                                  \
            pini(sqr[s]);                                                       \
        }                                                                       \
    } while (0)

// ---- kernel 2: threshold pass — per (row-tile, quarter) the 11 smallest of 64
//   slot-minima over 1024 distinct cols (each an ACTUAL int distance) -> Tv
__global__ __launch_bounds__(256, 2) void thresh_pass(
    const char* __restrict__ obsb, const int* __restrict__ sqi,
    int* __restrict__ Tv)
{
    __shared__ __align__(16) char Braw[2][BN * 512];    // 64 KB double buffer

    const int tid = threadIdx.x;
    const int wv = tid >> 6, ln = tid & 63;
    const int q  = blockIdx.x >> 7;          // quarter-sample 0..3
    const int rt = blockIdx.x & 127;         // row tile 0..127
    const int R0 = rt * BM;
    const int C0 = q * CPS;                  // sample = first 1024 cols of split q
    const int wrow0 = R0 + wv * 32;
    const int lr = ln & 15;
    const int kc = ln >> 4;
    const int lfrag = kc * 256 + lr * 16;

    i32x4 afrag[2][8];
    int sqr[2];
    LOAD_AFRAG();

    int segmin[2][16];
    #pragma unroll
    for (int s = 0; s < 2; ++s)
        #pragma unroll
        for (int p = 0; p < 16; ++p) segmin[s][p] = 0x7FFFFFFF;

    STAGE(0, 0);
    __syncthreads();
    #pragma unroll 2
    for (int it = 0; it < TITERS; ++it) {
        const int cur = it & 1;
        if (it + 1 < TITERS) STAGE(cur ^ 1, it + 1);
        GEMM_BODY(cur, it);
        #pragma unroll
        for (int s = 0; s < 2; ++s)
            #pragma unroll
            for (int cg = 0; cg < 4; ++cg)
                #pragma unroll
                for (int r = 0; r < 4; ++r)
                    segmin[s][cg * 4 + r] = min(segmin[s][cg * 4 + r], DIST(s, cg, r));
        __syncthreads();
    }

    // gather 64 slot-minima per row (stride 65) -> 11 smallest -> Tv[row][q][11]
    int* mins = (int*)&Braw[0][0];               // [BM][65] = 33 KB
    #pragma unroll
    for (int s = 0; s < 2; ++s)
        #pragma unroll
        for (int p = 0; p < 16; ++p)
            mins[(wv * 32 + s * 16 + lr) * 65 + kc * 16 + p] = segmin[s][p];
    __syncthreads();
    if (tid < BM) {
        int a[KSEL];
        topk_scan_i(mins + tid * 65, 64, a);
        #pragma unroll
        for (int p = 0; p < KSEL; ++p)
            Tv[(unsigned long)(R0 + tid) * (4 * KSEL) + q * KSEL + p] = a[p];
    }
}

// ---- kernel 3: T[row] = 11th smallest of the 44 quarter values
//   (44 actual distances at distinct columns => provable upper bound of true 11th)
__global__ void tmerge(const int* __restrict__ Tv, int* __restrict__ T) {
    const int row = blockIdx.x * 256 + threadIdx.x;
    int a[KSEL];
    T[row] = topk_scan_i(Tv + (unsigned long)row * (4 * KSEL), 4 * KSEL, a);
}

// ---- kernel 4: main pass — GEMM + rare predicated append (LDS counter, global vals)
__global__ __launch_bounds__(256, 2) void knn_main(
    const char* __restrict__ obsb, const int* __restrict__ sqi,
    const int* __restrict__ T, int* __restrict__ cnt,
    int* __restrict__ vals)
{
    __shared__ __align__(16) char Braw[2][BN * 512];    // 64 KB double buffer
    __shared__ unsigned lcnt[BM];

    const int tid = threadIdx.x;
    const int wv = tid >> 6, ln = tid & 63;
    const int sp = blockIdx.x >> 7;          // split 0..3
    const int rt = blockIdx.x & 127;         // row tile 0..127
    const int R0 = rt * BM;
    const int C0 = sp * CPS;
    const int wrow0 = R0 + wv * 32;
    const int lr = ln & 15;
    const int kc = ln >> 4;
    const int lfrag = kc * 256 + lr * 16;

    if (tid < BM) lcnt[tid] = 0u;

    i32x4 afrag[2][8];
    int sqr[2];
    LOAD_AFRAG();

    unsigned lrow[2]; int tval[2]; int* vbase[2];
    #pragma unroll
    for (int s = 0; s < 2; ++s) {
        const int row = wrow0 + s * 16 + lr;
        lrow[s]  = wv * 32 + s * 16 + lr;
        tval[s]  = T[row];                   // exact int gate, no slack needed
        pini(tval[s]);
        vbase[s] = vals + ((unsigned long)row * 4 + sp) * CAP;
    }

#define APP(S, VV) do {                                                         \
        const int v_ = (VV);                                                    \
        if (v_ <= tval[S]) {                                                    \
            const unsigned i_ = atomicAdd(&lcnt[lrow[S]], 1u);                  \
            if (i_ < CAP) vbase[S][i_] = v_;                                    \
        }                                                                       \
    } while (0)

    STAGE(0, 0);
    __syncthreads();
    #pragma unroll 2
    for (int it = 0; it < MITERS; ++it) {
        const int cur = it & 1;
        if (it + 1 < MITERS) STAGE(cur ^ 1, it + 1);
        GEMM_BODY(cur, it);
        #pragma unroll
        for (int s = 0; s < 2; ++s) {
            #pragma unroll
            for (int cg = 0; cg < 4; ++cg) {
                APP(s, DIST(s, cg, 0)); APP(s, DIST(s, cg, 1));
                APP(s, DIST(s, cg, 2)); APP(s, DIST(s, cg, 3));
            }
        }
        __syncthreads();
    }

    if (tid < BM) {
        const unsigned c = lcnt[tid];
        cnt[(unsigned long)(R0 + tid) * 4 + sp] = (int)(c < CAP ? c : CAP);
    }
}

// ---- kernel 5: per row, exact top-11 of appended int candidates -> output
__global__ void merge_out(const int* __restrict__ cnt, const int* __restrict__ vals,
                          float* __restrict__ out) {
    const int row = blockIdx.x * 256 + threadIdx.x;
    int arr[KSEL];
    #pragma unroll
    for (int p = 0; p < KSEL; ++p) arr[p] = 0x7FFFFFFF;
    int mx = 0x7FFFFFFF;
    for (int q = 0; q < 4; ++q) {
        const int n = min(cnt[(unsigned long)row * 4 + q], CAP);
        const int* base = vals + ((unsigned long)row * 4 + q) * CAP;
        for (int i = 0; i < n; ++i) {
            const int x = base[i];
            if (x < mx) {
                bool done = false;
                #pragma unroll
                for (int p = 0; p < KSEL; ++p) {
                    const bool rep = (!done) && (arr[p] == mx);
                    arr[p] = rep ? x : arr[p];
                    done = done || rep;
                }
                mx = arr[0];
                #pragma unroll
                for (int p = 1; p < KSEL; ++p) mx = max(mx, arr[p]);
            }
        }
    }
    int mn = arr[0];
    #pragma unroll
    for (int p = 1; p < KSEL; ++p) mn = min(mn, arr[p]);
    float ssum = 0.f;
    #pragma unroll
    for (int p = 0; p < KSEL; ++p) ssum += sqrtf((float)max(arr[p], 0));
    const float smn = sqrtf((float)max(mn, 0));
    out[row] = log1pf((ssum - smn) * (0.1f / QS));   // r = sqrt(d2i)/QS; mean of 10
}

extern "C" void kernel_launch(void* const* d_in, const int* in_sizes, int n_in,
                              void* d_out, int out_size, void* d_ws, size_t ws_size,
                              hipStream_t stream) {
    const float* obs = (const float*)d_in[0];
    float* out = (float*)d_out;
    char* ws = (char*)d_ws;

    char* obsb = ws;                                         // 8 MB fragment-major i8
    int*  sqi  = (int*)(ws + (size_t)NPTS * 512);            // 64 KB
    int*  T    = sqi + NPTS;                                 // 64 KB
    int*  cnt  = T + NPTS;                                   // 256 KB
    int*  vals = cnt + NPTS * 4;                             // 12 MB (CAP=48)
    int*  Tv   = vals;   // aliased: Tv (2.75 MB) is consumed by tmerge BEFORE
                         // knn_main writes vals (stream-ordered, no overlap)

    prep_convert<<<NPTS / 4, 256, 0, stream>>>(obs, obsb, sqi);
    thresh_pass<<<128 * 4, 256, 0, stream>>>(obsb, sqi, Tv);
    tmerge<<<NPTS / 256, 256, 0, stream>>>(Tv, T);
    knn_main<<<128 * NSPLIT, 256, 0, stream>>>(obsb, sqi, T, cnt, vals);
    merge_out<<<NPTS / 256, 256, 0, stream>>>(cnt, vals, out);
}

// Round 14
// 267.353 us; speedup vs baseline: 3.1961x; 1.0661x over previous
//
#include <hip/hip_runtime.h>
#include <math.h>

// ---- problem constants (fixed shapes) ----
#define NPTS 16384
#define DIM  512
#define KSEL 11                   // K+1 smallest incl. self; min dropped at the end
#define NSPLIT 8
#define CPS   (NPTS / NSPLIT)     // 2048 columns per split (main)
#define BMM   256                 // knn_main rows per block (4 waves x 64 rows)
#define BMT   128                 // thresh rows per block (4 waves x 32 rows)
#define BN    64                  // columns staged per iteration (32 KB in i8)
#define MITERS (CPS / BN)         // 32 main iterations per split
#define TITERS 16                 // threshold pass: 1024 cols per quarter-sample
#define TCH   4096                // thresh quarter stride (sample = first 1024 of each)
#define STRIPB 8192               // bytes per 16-row/col fragment-major strip (i8)
#define CAP   24                  // appended candidates per (row, split)
#define QS    22.0f               // quantization scale: x_i8 = clamp(rint(22 x), +-127)

typedef __attribute__((ext_vector_type(4))) int i32x4;

__device__ __forceinline__ void gload_lds16(const void* g, void* l) {
    __builtin_amdgcn_global_load_lds(
        (const __attribute__((address_space(1))) void*)g,
        (__attribute__((address_space(3))) void*)l, 16, 0, 0);
}

__device__ __forceinline__ void pinreg(i32x4& v) { asm volatile("" : "+v"(v)); }
__device__ __forceinline__ void pini(int& v)     { asm volatile("" : "+v"(v)); }

// exact KSEL-smallest scan over ints v[0..n), n >= KSEL; a[] gets them; returns the KSEL-th
__device__ __forceinline__ int topk_scan_i(const int* v, int n, int* a) {
    #pragma unroll
    for (int p = 0; p < KSEL; ++p) a[p] = v[p];
    int mx = a[0];
    #pragma unroll
    for (int p = 1; p < KSEL; ++p) mx = max(mx, a[p]);
    for (int i = KSEL; i < n; ++i) {
        const int x = v[i];
        if (x < mx) {
            bool done = false;
            #pragma unroll
            for (int p = 0; p < KSEL; ++p) {
                const bool rep = (!done) && (a[p] == mx);
                a[p] = rep ? x : a[p];
                done = done || rep;
            }
            mx = a[0];
            #pragma unroll
            for (int p = 1; p < KSEL; ++p) mx = max(mx, a[p]);
        }
    }
    return mx;
}

// ---- kernel 1: fp32 -> i8 quantize into K=64 fragment-major layout + sqi = ||xi8||^2
//   byte(row,k) = (row>>4)*8192 + (k>>6)*1024 + ((k>>4)&3)*256 + (row&15)*16 + (k&15)
__global__ void prep_convert(const float* __restrict__ obs, char* __restrict__ obsb,
                             int* __restrict__ sqi) {
    const int wv = threadIdx.x >> 6, ln = threadIdx.x & 63;
    const int row = blockIdx.x * 4 + wv;
    const float4* s = (const float4*)(obs + (unsigned long)row * DIM + ln * 8);
    const float4 a = s[0], b = s[1];
    float xs[8] = {a.x, a.y, a.z, a.w, b.x, b.y, b.z, b.w};
    unsigned long u = 0ul;
    int ssum = 0;
    #pragma unroll
    for (int j = 0; j < 8; ++j) {
        const int q = __float2int_rn(fminf(fmaxf(xs[j] * QS, -127.f), 127.f));
        ssum += q * q;
        u |= ((unsigned long)((unsigned)q & 0xffu)) << (8 * j);
    }
    *(unsigned long*)(obsb + (unsigned long)(row >> 4) * STRIPB + (ln >> 3) * 1024
                      + ((ln >> 1) & 3) * 256 + (row & 15) * 16 + (ln & 1) * 8) = u;
    #pragma unroll
    for (int off = 32; off; off >>= 1) ssum += __shfl_xor(ssum, off);
    if (ln == 0) sqi[row] = ssum;
}

// ---- shared 2-phase double-buffer macros (BN=64 tile: 4 strips, wave wv stages strip wv)
#define STAGE(BUF, CITER) do {                                                  \
        const char* gs_ = obsb + (unsigned long)((C0 >> 4) + 4 * (CITER)) * STRIPB \
                          + wv * 8192 + ln * 16;                                \
        char* lb_ = &Braw[BUF][0] + wv * 8192;                                  \
        _Pragma("unroll")                                                       \
        for (int r_ = 0; r_ < 8; ++r_)                                          \
            gload_lds16(gs_ + r_ * 1024, lb_ + r_ * 1024);                      \
    } while (0)

// 2-strip body (thresh)
#define GEMM_BODY(CUR, CITER)                                                   \
        const char* bp = &Braw[CUR][0];                                         \
        i32x4 acc[2][4] = {{{0,0,0,0},{0,0,0,0},{0,0,0,0},{0,0,0,0}},           \
                           {{0,0,0,0},{0,0,0,0},{0,0,0,0},{0,0,0,0}}};          \
        _Pragma("unroll")                                                       \
        for (int cg = 0; cg < 4; ++cg) {                                        \
            _Pragma("unroll")                                                   \
            for (int t = 0; t < 8; ++t) {                                       \
                const i32x4 b = *(const i32x4*)(bp + cg * STRIPB + t * 1024 + lfrag); \
                acc[0][cg] = __builtin_amdgcn_mfma_i32_16x16x64_i8(b, afrag[0][t], acc[0][cg], 0, 0, 0); \
                acc[1][cg] = __builtin_amdgcn_mfma_i32_16x16x64_i8(b, afrag[1][t], acc[1][cg], 0, 0, 0); \
            }                                                                   \
        }                                                                       \
        i32x4 sqv[4];                                                           \
        _Pragma("unroll")                                                       \
        for (int cg_ = 0; cg_ < 4; ++cg_)                                       \
            sqv[cg_] = *(const i32x4*)(sqi + C0 + (CITER) * BN + cg_ * 16 + kc * 4);

#define DIST(S, CG, R) (sqr[S] + sqv[CG][R] - 2 * acc[S][CG][R])

#define LOAD_AFRAG() do {                                                       \
        _Pragma("unroll")                                                       \
        for (int s = 0; s < 2; ++s) {                                           \
            const unsigned long sbase = (unsigned long)((R0 >> 4) + wv * 2 + s) * STRIPB; \
            _Pragma("unroll")                                                   \
            for (int t = 0; t < 8; ++t) {                                       \
                afrag[s][t] = *(const i32x4*)(obsb + sbase + t * 1024 + lfrag); \
                pinreg(afrag[s][t]);                                            \
            }                                                                   \
            sqr[s] = sqi[wrow0 + s * 16 + lr];                                  \
            pini(sqr[s]);                                                       \
        }                                                                       \
    } while (0)

// ---- kernel 2: threshold pass (UNCHANGED geometry: BMT=128, 2 strips/wave) ----
//   per (row-tile, quarter): 11 smallest of 64 slot-minima over 1024 distinct cols
__global__ __launch_bounds__(256, 2) void thresh_pass(
    const char* __restrict__ obsb, const int* __restrict__ sqi,
    int* __restrict__ Tv)
{
    __shared__ __align__(16) char Braw[2][BN * 512];    // 64 KB double buffer

    const int tid = threadIdx.x;
    const int wv = tid >> 6, ln = tid & 63;
    const int q  = blockIdx.x >> 7;          // quarter-sample 0..3
    const int rt = blockIdx.x & 127;         // row tile 0..127
    const int R0 = rt * BMT;
    const int C0 = q * TCH;                  // sample = first 1024 cols of chunk q
    const int wrow0 = R0 + wv * 32;
    const int lr = ln & 15;
    const int kc = ln >> 4;
    const int lfrag = kc * 256 + lr * 16;

    i32x4 afrag[2][8];
    int sqr[2];
    LOAD_AFRAG();

    int segmin[2][16];
    #pragma unroll
    for (int s = 0; s < 2; ++s)
        #pragma unroll
        for (int p = 0; p < 16; ++p) segmin[s][p] = 0x7FFFFFFF;

    STAGE(0, 0);
    __syncthreads();
    #pragma unroll 2
    for (int it = 0; it < TITERS; ++it) {
        const int cur = it & 1;
        if (it + 1 < TITERS) STAGE(cur ^ 1, it + 1);
        GEMM_BODY(cur, it);
        #pragma unroll
        for (int s = 0; s < 2; ++s)
            #pragma unroll
            for (int cg = 0; cg < 4; ++cg)
                #pragma unroll
                for (int r = 0; r < 4; ++r)
                    segmin[s][cg * 4 + r] = min(segmin[s][cg * 4 + r], DIST(s, cg, r));
        __syncthreads();
    }

    int* mins = (int*)&Braw[0][0];               // [BMT][65] = 33 KB
    #pragma unroll
    for (int s = 0; s < 2; ++s)
        #pragma unroll
        for (int p = 0; p < 16; ++p)
            mins[(wv * 32 + s * 16 + lr) * 65 + kc * 16 + p] = segmin[s][p];
    __syncthreads();
    if (tid < BMT) {
        int a[KSEL];
        topk_scan_i(mins + tid * 65, 64, a);
        #pragma unroll
        for (int p = 0; p < KSEL; ++p)
            Tv[(unsigned long)(R0 + tid) * (4 * KSEL) + q * KSEL + p] = a[p];
    }
}

// ---- kernel 3: T[row] = 11th smallest of the 44 quarter values (provable upper bound)
__global__ void tmerge(const int* __restrict__ Tv, int* __restrict__ T) {
    const int row = blockIdx.x * 256 + threadIdx.x;
    int a[KSEL];
    T[row] = topk_scan_i(Tv + (unsigned long)row * (4 * KSEL), 4 * KSEL, a);
}

// ---- kernel 4: main pass — 4 strips/wave (64 rows): B LDS-reads reused 4x
__global__ __launch_bounds__(256, 2) void knn_main(
    const char* __restrict__ obsb, const int* __restrict__ sqi,
    const int* __restrict__ T, int* __restrict__ cnt,
    int* __restrict__ vals)
{
    __shared__ __align__(16) char Braw[2][BN * 512];    // 64 KB double buffer
    __shared__ unsigned lcnt[BMM];

    const int tid = threadIdx.x;
    const int wv = tid >> 6, ln = tid & 63;
    const int sp = blockIdx.x >> 6;          // split 0..7
    const int rt = blockIdx.x & 63;          // row tile 0..63
    const int R0 = rt * BMM;
    const int C0 = sp * CPS;
    const int wrow0 = R0 + wv * 64;
    const int lr = ln & 15;
    const int kc = ln >> 4;
    const int lfrag = kc * 256 + lr * 16;

    lcnt[tid] = 0u;

    // A fragments: 4 strips x 8 t-steps (128 VGPRs), pinned
    i32x4 afrag[4][8];
    int sqr[4];
    #pragma unroll
    for (int s = 0; s < 4; ++s) {
        const unsigned long sbase = (unsigned long)((R0 >> 4) + wv * 4 + s) * STRIPB;
        #pragma unroll
        for (int t = 0; t < 8; ++t) {
            afrag[s][t] = *(const i32x4*)(obsb + sbase + t * 1024 + lfrag);
            pinreg(afrag[s][t]);
        }
        sqr[s] = sqi[wrow0 + s * 16 + lr];
        pini(sqr[s]);
    }

    unsigned lrow[4]; int tval[4]; int* vbase[4];
    #pragma unroll
    for (int s = 0; s < 4; ++s) {
        const int row = wrow0 + s * 16 + lr;
        lrow[s]  = wv * 64 + s * 16 + lr;
        tval[s]  = T[row];                   // exact int gate
        pini(tval[s]);
        vbase[s] = vals + ((unsigned long)row * NSPLIT + sp) * CAP;
    }

    STAGE(0, 0);
    __syncthreads();
    #pragma unroll 2
    for (int it = 0; it < MITERS; ++it) {
        const int cur = it & 1;
        if (it + 1 < MITERS) STAGE(cur ^ 1, it + 1);
        // 4-strip GEMM body: 32 ds_read_b128, 128 MFMA (each b reused 4x)
        const char* bp = &Braw[cur][0];
        i32x4 acc[4][4];
        #pragma unroll
        for (int s_ = 0; s_ < 4; ++s_)
            #pragma unroll
            for (int c_ = 0; c_ < 4; ++c_) acc[s_][c_] = (i32x4){0, 0, 0, 0};
        #pragma unroll
        for (int cg = 0; cg < 4; ++cg) {
            #pragma unroll
            for (int t = 0; t < 8; ++t) {
                const i32x4 b = *(const i32x4*)(bp + cg * STRIPB + t * 1024 + lfrag);
                #pragma unroll
                for (int s_ = 0; s_ < 4; ++s_)
                    acc[s_][cg] = __builtin_amdgcn_mfma_i32_16x16x64_i8(
                        b, afrag[s_][t], acc[s_][cg], 0, 0, 0);
            }
        }
        i32x4 sqv[4];
        #pragma unroll
        for (int c_ = 0; c_ < 4; ++c_)
            sqv[c_] = *(const i32x4*)(sqi + C0 + it * BN + c_ * 16 + kc * 4);
        // rare predicated append
        #pragma unroll
        for (int s_ = 0; s_ < 4; ++s_)
            #pragma unroll
            for (int cg = 0; cg < 4; ++cg)
                #pragma unroll
                for (int r = 0; r < 4; ++r) {
                    const int v_ = sqr[s_] + sqv[cg][r] - 2 * acc[s_][cg][r];
                    if (v_ <= tval[s_]) {
                        const unsigned i_ = atomicAdd(&lcnt[lrow[s_]], 1u);
                        if (i_ < CAP) vbase[s_][i_] = v_;
                    }
                }
        __syncthreads();
    }

    {
        const unsigned c = lcnt[tid];
        cnt[(unsigned long)(R0 + tid) * NSPLIT + sp] = (int)(c < CAP ? c : CAP);
    }
}

// ---- kernel 5: per row, exact top-11 of appended int candidates -> output
__global__ void merge_out(const int* __restrict__ cnt, const int* __restrict__ vals,
                          float* __restrict__ out) {
    const int row = blockIdx.x * 256 + threadIdx.x;
    int arr[KSEL];
    #pragma unroll
    for (int p = 0; p < KSEL; ++p) arr[p] = 0x7FFFFFFF;
    int mx = 0x7FFFFFFF;
    for (int q = 0; q < NSPLIT; ++q) {
        const int n = min(cnt[(unsigned long)row * NSPLIT + q], CAP);
        const int* base = vals + ((unsigned long)row * NSPLIT + q) * CAP;
        for (int i = 0; i < n; ++i) {
            const int x = base[i];
            if (x < mx) {
                bool done = false;
                #pragma unroll
                for (int p = 0; p < KSEL; ++p) {
                    const bool rep = (!done) && (arr[p] == mx);
                    arr[p] = rep ? x : arr[p];
                    done = done || rep;
                }
                mx = arr[0];
                #pragma unroll
                for (int p = 1; p < KSEL; ++p) mx = max(mx, arr[p]);
            }
        }
    }
    int mn = arr[0];
    #pragma unroll
    for (int p = 1; p < KSEL; ++p) mn = min(mn, arr[p]);
    float ssum = 0.f;
    #pragma unroll
    for (int p = 0; p < KSEL; ++p) ssum += sqrtf((float)max(arr[p], 0));
    const float smn = sqrtf((float)max(mn, 0));
    out[row] = log1pf((ssum - smn) * (0.1f / QS));   // r = sqrt(d2i)/QS; mean of 10
}

extern "C" void kernel_launch(void* const* d_in, const int* in_sizes, int n_in,
                              void* d_out, int out_size, void* d_ws, size_t ws_size,
                              hipStream_t stream) {
    const float* obs = (const float*)d_in[0];
    float* out = (float*)d_out;
    char* ws = (char*)d_ws;

    char* obsb = ws;                                         // 8 MB fragment-major i8
    int*  sqi  = (int*)(ws + (size_t)NPTS * 512);            // 64 KB
    int*  T    = sqi + NPTS;                                 // 64 KB
    int*  cnt  = T + NPTS;                                   // 512 KB
    int*  vals = cnt + NPTS * NSPLIT;                        // 12.6 MB (8 x CAP=24)
    int*  Tv   = vals;   // aliased: Tv (2.75 MB) consumed by tmerge BEFORE
                         // knn_main writes vals (stream-ordered, no overlap)

    prep_convert<<<NPTS / 4, 256, 0, stream>>>(obs, obsb, sqi);
    thresh_pass<<<128 * 4, 256, 0, stream>>>(obsb, sqi, Tv);
    tmerge<<<NPTS / 256, 256, 0, stream>>>(Tv, T);
    knn_main<<<64 * NSPLIT, 256, 0, stream>>>(obsb, sqi, T, cnt, vals);
    merge_out<<<NPTS / 256, 256, 0, stream>>>(cnt, vals, out);
}